// Round 2
// baseline (1337.554 us; speedup 1.0000x reference)
//
#include <hip/hip_runtime.h>
#include <stdint.h>

// net_gcn_multitask — GCN 2-layer + self-supervised branch, MI355X
//
// Pipeline:
//   t = spmm(x)                (CSR gather, built on-device per call)
//   u = relu(t @ W0)           (in-place on t)
//   m1,m2 = threefry bernoulli masks (JAX key(42), PARTITIONABLE scheme)
//   h = spmm(where(m1,u/.8,0)) @ W1   -> d_out[0 .. 4M)
//   s = spmm(where(m2,u/.8,0)) @ Wss  -> d_out[4M .. 10.4M)

#define NN 100000
#define NE 1600000
#define D 128
#define NW 400000       // mask words per mask: NN*D/32
#define DO1 40
#define DO2 64
#define OUT_S_OFF 4000000
#define KEEP_THR 6710886u  // (bits>>9) <= this  <=>  uniform < 0.8f

// ---------------- threefry2x32 (JAX-compatible, 20 rounds) ----------------
__device__ __forceinline__ void tf2x32(uint32_t k0, uint32_t k1,
                                       uint32_t x0, uint32_t x1,
                                       uint32_t& o0, uint32_t& o1) {
  uint32_t ks2 = k0 ^ k1 ^ 0x1BD11BDAu;
  x0 += k0; x1 += k1;
#define TFR(r) { x0 += x1; x1 = (x1 << (r)) | (x1 >> (32 - (r))); x1 ^= x0; }
  TFR(13) TFR(15) TFR(26) TFR(6)
  x0 += k1;  x1 += ks2 + 1u;
  TFR(17) TFR(29) TFR(16) TFR(24)
  x0 += ks2; x1 += k0 + 2u;
  TFR(13) TFR(15) TFR(26) TFR(6)
  x0 += k0;  x1 += k1 + 3u;
  TFR(17) TFR(29) TFR(16) TFR(24)
  x0 += k1;  x1 += ks2 + 4u;
  TFR(13) TFR(15) TFR(26) TFR(6)
  x0 += ks2; x1 += k0 + 5u;
#undef TFR
  o0 = x0; o1 = x1;
}

// Partitionable threefry (JAX >= 0.4.30 default):
//   split(key)[i]   = (o0,o1) of block (x0=0, x1=i) under parent key
//   bits32(key, e)  = o0 ^ o1 of block (x0=hi(e)=0, x1=lo(e)=e)
// One thread per (mask, word): 32 evals -> one 32-bit mask word.
__global__ void mask_kernel(uint32_t* __restrict__ m1, uint32_t* __restrict__ m2) {
  int t = blockIdx.x * blockDim.x + threadIdx.x;
  if (t >= 2 * NW) return;
  uint32_t a0, a1, b0, b1;
  tf2x32(0u, 42u, 0u, 0u, a0, a1);   // child key 0 (constant-folded)
  tf2x32(0u, 42u, 0u, 1u, b0, b1);   // child key 1
  bool second = (t >= NW);
  uint32_t w  = second ? (uint32_t)(t - NW) : (uint32_t)t;
  uint32_t k0 = second ? b0 : a0;
  uint32_t k1 = second ? b1 : a1;
  uint32_t base = w * 32u;
  uint32_t word = 0u;
  for (int i = 0; i < 32; ++i) {
    uint32_t o0, o1;
    tf2x32(k0, k1, 0u, base + (uint32_t)i, o0, o1);
    uint32_t bits = o0 ^ o1;
    word |= (uint32_t)((bits >> 9) <= KEEP_THR) << i;
  }
  (second ? m2 : m1)[w] = word;
}

// ---------------- CSR build ----------------
__global__ void hist_kernel(const int* __restrict__ row, int* __restrict__ cnt) {
  int e = blockIdx.x * blockDim.x + threadIdx.x;
  if (e < NE) atomicAdd(&cnt[row[e]], 1);
}

__global__ void scan_kernel(const int* __restrict__ cnt, int* __restrict__ ptr, int n) {
  __shared__ int smem[1024];
  __shared__ int carry;
  if (threadIdx.x == 0) carry = 0;
  __syncthreads();
  for (int base = 0; base < n; base += 1024) {
    int i = base + (int)threadIdx.x;
    int v = (i < n) ? cnt[i] : 0;
    smem[threadIdx.x] = v;
    __syncthreads();
    for (int off = 1; off < 1024; off <<= 1) {
      int add = (threadIdx.x >= (unsigned)off) ? smem[threadIdx.x - off] : 0;
      __syncthreads();
      smem[threadIdx.x] += add;
      __syncthreads();
    }
    if (i < n) ptr[i] = carry + (smem[threadIdx.x] - v);  // exclusive
    __syncthreads();
    if (threadIdx.x == 0) carry += smem[1023];
    __syncthreads();
  }
  if (threadIdx.x == 0) ptr[n] = carry;
}

__global__ void scatter_kernel(const int* __restrict__ row, const int* __restrict__ col,
                               const float* __restrict__ val, int* __restrict__ cursor,
                               int* __restrict__ col_s, float* __restrict__ val_s) {
  int e = blockIdx.x * blockDim.x + threadIdx.x;
  if (e < NE) {
    int r = row[e];
    int p = atomicAdd(&cursor[r], 1);
    col_s[p] = col[e];
    val_s[p] = val[e];
  }
}

// ---------------- t = spmm(x): one block (128 thr) per row ----------------
__global__ void spmm_x_kernel(const int* __restrict__ ptr, const int* __restrict__ col_s,
                              const float* __restrict__ val_s, const float* __restrict__ x,
                              float* __restrict__ t) {
  int r = blockIdx.x;
  int k = threadIdx.x;
  int s = ptr[r], e = ptr[r + 1];
  float acc = 0.f;
  for (int i = s; i < e; ++i) {
    int c = col_s[i];
    float v = val_s[i];
    acc += v * x[(size_t)c * D + k];
  }
  t[(size_t)r * D + k] = acc;
}

// ---------------- u = relu(t @ W0), in place ----------------
#define ROWS_U 64
__global__ void gemm_relu_kernel(float* __restrict__ t, const float* __restrict__ W0) {
  __shared__ float w[D * D];    // 64 KB (gfx950 allows up to 160 KB)
  __shared__ float rowbuf[D];
  int tid = threadIdx.x;        // 128 threads; tid = output column
  for (int i = tid; i < D * D; i += 128) w[i] = W0[i];
  __syncthreads();
  int r0 = blockIdx.x * ROWS_U;
  for (int rr = 0; rr < ROWS_U; ++rr) {
    int r = r0 + rr;
    if (r >= NN) break;
    rowbuf[tid] = t[(size_t)r * D + tid];
    __syncthreads();
    float acc = 0.f;
#pragma unroll 8
    for (int k = 0; k < D; ++k) acc += rowbuf[k] * w[k * D + tid];
    acc = fmaxf(acc, 0.f);
    __syncthreads();
    t[(size_t)r * D + tid] = acc;
  }
}

// ---- fused: y1=spmm(drop1(u)), y2=spmm(drop2(u)); h=y1@W1; s=y2@Wss ----
#define ROWS_F 8
__global__ void fused_out_kernel(const int* __restrict__ ptr, const int* __restrict__ col_s,
                                 const float* __restrict__ val_s, const float* __restrict__ u,
                                 const uint32_t* __restrict__ m1, const uint32_t* __restrict__ m2,
                                 const float* __restrict__ W1, const float* __restrict__ Wss,
                                 float* __restrict__ out) {
  __shared__ float acc1[D];
  __shared__ float acc2[D];
  int tid = threadIdx.x;  // 128
  int wsel = tid >> 5, bsel = tid & 31;
  int r0 = blockIdx.x * ROWS_F;
  for (int rr = 0; rr < ROWS_F; ++rr) {
    int r = r0 + rr;
    if (r >= NN) break;
    int s = ptr[r], e = ptr[r + 1];
    float a1 = 0.f, a2 = 0.f;
    for (int i = s; i < e; ++i) {
      int c = col_s[i];
      float v = val_s[i];
      float uc = u[(size_t)c * D + tid] * 1.25f;  // 1/keep
      uint32_t w1 = m1[c * 4 + wsel];
      uint32_t w2 = m2[c * 4 + wsel];
      if ((w1 >> bsel) & 1u) a1 += v * uc;
      if ((w2 >> bsel) & 1u) a2 += v * uc;
    }
    acc1[tid] = a1;
    acc2[tid] = a2;
    __syncthreads();
    if (tid < DO1) {
      float h = 0.f;
#pragma unroll 8
      for (int k = 0; k < D; ++k) h += acc1[k] * W1[k * DO1 + tid];
      out[(size_t)r * DO1 + tid] = h;
    } else if (tid >= 64) {
      int j = tid - 64;
      float sa = 0.f;
#pragma unroll 8
      for (int k = 0; k < D; ++k) sa += acc2[k] * Wss[k * DO2 + j];
      out[OUT_S_OFF + (size_t)r * DO2 + j] = sa;
    }
    __syncthreads();
  }
}

// ---------------- launch ----------------
extern "C" void kernel_launch(void* const* d_in, const int* in_sizes, int n_in,
                              void* d_out, int out_size, void* d_ws, size_t ws_size,
                              hipStream_t stream) {
  const float* x       = (const float*)d_in[0];
  const int*   adj_row = (const int*)d_in[1];
  const int*   adj_col = (const int*)d_in[2];
  const float* adj_val = (const float*)d_in[3];
  const float* W0      = (const float*)d_in[4];
  const float* W1      = (const float*)d_in[5];
  const float* Wss     = (const float*)d_in[6];
  float* out = (float*)d_out;

  char* ws = (char*)d_ws;
  float*    t     = (float*)(ws + 0);           // 51,200,000 B
  uint32_t* m1    = (uint32_t*)(ws + 51200000); //  1,600,000 B
  uint32_t* m2    = (uint32_t*)(ws + 52800000); //  1,600,000 B
  int*      ptr   = (int*)(ws + 54400000);      //    400,016 B (N+1 ints)
  int*      cnt   = (int*)(ws + 54800016);      //    400,000 B
  int*      cur   = (int*)(ws + 55200016);      //    400,000 B
  int*      col_s = (int*)(ws + 55600016);      //  6,400,000 B
  float*    val_s = (float*)(ws + 62000016);    //  6,400,000 B  (end 68,400,016)

  hipMemsetAsync(cnt, 0, NN * sizeof(int), stream);
  mask_kernel<<<(2 * NW + 255) / 256, 256, 0, stream>>>(m1, m2);
  hist_kernel<<<(NE + 255) / 256, 256, 0, stream>>>(adj_row, cnt);
  scan_kernel<<<1, 1024, 0, stream>>>(cnt, ptr, NN);
  hipMemcpyAsync(cur, ptr, NN * sizeof(int), hipMemcpyDeviceToDevice, stream);
  scatter_kernel<<<(NE + 255) / 256, 256, 0, stream>>>(adj_row, adj_col, adj_val,
                                                       cur, col_s, val_s);
  spmm_x_kernel<<<NN, 128, 0, stream>>>(ptr, col_s, val_s, x, t);
  gemm_relu_kernel<<<(NN + ROWS_U - 1) / ROWS_U, 128, 0, stream>>>(t, W0);
  fused_out_kernel<<<NN / ROWS_F, 128, 0, stream>>>(ptr, col_s, val_s, t, m1, m2,
                                                    W1, Wss, out);
}

// Round 4
// 774.235 us; speedup vs baseline: 1.7276x; 1.7276x over previous
//
#include <hip/hip_runtime.h>
#include <stdint.h>

// net_gcn_multitask — MI355X. Pipeline (fp32 math, bf16 storage for gathers):
//   xb = bf16(x)
//   t  = spmm(xb)                       [wave-per-row gather]
//   z  = [drop1(relu(t@W0))@W1 | drop2(relu(t@W0))@Wss]   (bf16, stride 104)
//   out: h = spmm(z)[:, :40], s = spmm(z)[:, 40:]          [wave-per-row gather]
// CSR built on device (hist -> 3-phase scan -> scatter).

#define NN 100000
#define NE 1600000
#define D 128
#define NW 400000        // mask words per mask: NN*D/32
#define ZC 104           // z columns (40 + 64)
#define DO1 40
#define DO2 64
#define OUT_S_OFF 4000000
#define KEEP_THR 6710886u
#define USTRIDE 132      // u-quarter row stride (128 cols + pad, 16B-aligned rows)

typedef unsigned int uint;

// ---------------- bf16 helpers ----------------
__device__ __forceinline__ float bflo(uint p) { return __uint_as_float(p << 16); }
__device__ __forceinline__ float bfhi(uint p) { return __uint_as_float(p & 0xffff0000u); }
__device__ __forceinline__ uint f2bf(float f) {
  uint u = __float_as_uint(f);
  return (u + 0x7fffu + ((u >> 16) & 1u)) >> 16;   // RTNE
}
__device__ __forceinline__ uint pack2(float lo, float hi) {
  return f2bf(lo) | (f2bf(hi) << 16);
}

// ---------------- threefry2x32 (JAX partitionable; verified round 2) ------
__device__ __forceinline__ void tf2x32(uint k0, uint k1, uint x0, uint x1,
                                       uint& o0, uint& o1) {
  uint ks2 = k0 ^ k1 ^ 0x1BD11BDAu;
  x0 += k0; x1 += k1;
#define TFR(r) { x0 += x1; x1 = (x1 << (r)) | (x1 >> (32 - (r))); x1 ^= x0; }
  TFR(13) TFR(15) TFR(26) TFR(6)
  x0 += k1;  x1 += ks2 + 1u;
  TFR(17) TFR(29) TFR(16) TFR(24)
  x0 += ks2; x1 += k0 + 2u;
  TFR(13) TFR(15) TFR(26) TFR(6)
  x0 += k0;  x1 += k1 + 3u;
  TFR(17) TFR(29) TFR(16) TFR(24)
  x0 += k1;  x1 += ks2 + 4u;
  TFR(13) TFR(15) TFR(26) TFR(6)
  x0 += ks2; x1 += k0 + 5u;
#undef TFR
  o0 = x0; o1 = x1;
}

__global__ void mask_kernel(uint* __restrict__ m1, uint* __restrict__ m2) {
  int t = blockIdx.x * blockDim.x + threadIdx.x;
  if (t >= 2 * NW) return;
  uint a0, a1, b0, b1;
  tf2x32(0u, 42u, 0u, 0u, a0, a1);
  tf2x32(0u, 42u, 0u, 1u, b0, b1);
  bool second = (t >= NW);
  uint w  = second ? (uint)(t - NW) : (uint)t;
  uint k0 = second ? b0 : a0;
  uint k1 = second ? b1 : a1;
  uint base = w * 32u;
  uint word = 0u;
  for (int i = 0; i < 32; ++i) {
    uint o0, o1;
    tf2x32(k0, k1, 0u, base + (uint)i, o0, o1);
    word |= (uint)(((o0 ^ o1) >> 9) <= KEEP_THR) << i;
  }
  (second ? m2 : m1)[w] = word;
}

// ---------------- x -> bf16 ----------------
__global__ void convx_kernel(const float* __restrict__ x, uint* __restrict__ xb) {
  int i = blockIdx.x * blockDim.x + threadIdx.x;   // 6.4M threads, 2 floats each
  float2 v = ((const float2*)x)[i];
  xb[i] = pack2(v.x, v.y);
}

// ---------------- CSR build ----------------
__global__ void hist_kernel(const int* __restrict__ row, int* __restrict__ cnt) {
  int e = blockIdx.x * blockDim.x + threadIdx.x;
  if (e < NE) atomicAdd(&cnt[row[e]], 1);
}

// 3-phase scan: 98 blocks x 1024 elements
__global__ void scan_reduce(const int* __restrict__ cnt, int* __restrict__ aux) {
  __shared__ int sb[256];
  int b = blockIdx.x, t = threadIdx.x;
  int base = b * 1024 + t * 4, s = 0;
#pragma unroll
  for (int j = 0; j < 4; ++j) { int i = base + j; s += (i < NN) ? cnt[i] : 0; }
  sb[t] = s; __syncthreads();
  for (int off = 128; off > 0; off >>= 1) {
    if (t < off) sb[t] += sb[t + off];
    __syncthreads();
  }
  if (t == 0) aux[b] = sb[0];
}

__global__ void scan_aux(int* __restrict__ aux, int* __restrict__ ptr) {
  __shared__ int sb[128];
  int t = threadIdx.x;
  int v = (t < 98) ? aux[t] : 0;
  sb[t] = v; __syncthreads();
  for (int off = 1; off < 128; off <<= 1) {
    int a = (t >= off) ? sb[t - off] : 0;
    __syncthreads();
    sb[t] += a;
    __syncthreads();
  }
  if (t < 98) aux[t] = sb[t] - v;   // exclusive
  if (t == 127) ptr[NN] = sb[127];
}

__global__ void scan_apply(const int* __restrict__ cnt, const int* __restrict__ aux,
                           int* __restrict__ ptr) {
  __shared__ int sb[256];
  int b = blockIdx.x, t = threadIdx.x;
  int base = b * 1024 + t * 4;
  int c[4], ts = 0;
#pragma unroll
  for (int j = 0; j < 4; ++j) { int i = base + j; c[j] = (i < NN) ? cnt[i] : 0; ts += c[j]; }
  sb[t] = ts; __syncthreads();
  for (int off = 1; off < 256; off <<= 1) {
    int a = (t >= off) ? sb[t - off] : 0;
    __syncthreads();
    sb[t] += a;
    __syncthreads();
  }
  int off0 = aux[b] + sb[t] - ts;
#pragma unroll
  for (int j = 0; j < 4; ++j) {
    int i = base + j;
    if (i < NN) ptr[i] = off0;
    off0 += c[j];
  }
}

__global__ void scatter_kernel(const int* __restrict__ row, const int* __restrict__ col,
                               const float* __restrict__ val, int* __restrict__ cursor,
                               int* __restrict__ col_s, float* __restrict__ val_s) {
  int e = blockIdx.x * blockDim.x + threadIdx.x;
  if (e < NE) {
    int r = row[e];
    int p = atomicAdd(&cursor[r], 1);
    col_s[p] = col[e];
    val_s[p] = val[e];
  }
}

// ---------------- t = spmm(xb): wave per row, bf16 in/out ----------------
__global__ void spmm_x_kernel(const int* __restrict__ ptr, const int* __restrict__ col_s,
                              const float* __restrict__ val_s, const uint* __restrict__ xb,
                              uint* __restrict__ t) {
  int r = blockIdx.x * 4 + (threadIdx.x >> 6);
  int lane = threadIdx.x & 63;
  int s = ptr[r], e = ptr[r + 1];
  float ax = 0.f, ay = 0.f;
  for (int i = s; i < e; ++i) {
    int c = col_s[i];
    float v = val_s[i];
    uint p = xb[c * 64 + lane];
    ax += v * bflo(p);
    ay += v * bfhi(p);
  }
  t[r * 64 + lane] = pack2(ax, ay);
}

// ---- pass A: z = [drop1(relu(t@W0))@W1 | drop2(relu(t@W0))@Wss], bf16 ----
// 256 thr, 128-row tile. t/W0 tiles in LDS; epilogue per 32-row quarter.
__global__ __launch_bounds__(256) void pass_a_kernel(
    const uint* __restrict__ tb, const float* __restrict__ W0,
    const float* __restrict__ W1, const float* __restrict__ Wss,
    const uint* __restrict__ m1, const uint* __restrict__ m2,
    ushort* __restrict__ zz) {
  __shared__ __align__(16) float pool[8704];   // 34816 B
  float* t_lds  = pool;          // [128][36]  (main loop)
  float* w0_lds = pool + 4608;   // [32][128]  (main loop)
  float* u1q = pool;             // [32][USTRIDE] (epilogue)
  float* u2q = pool + 32 * USTRIDE;

  int t  = threadIdx.x;
  int tc = t & 15, tr = t >> 4;
  int r0 = blockIdx.x * 128;

  float acc[8][8];
#pragma unroll
  for (int i = 0; i < 8; ++i)
#pragma unroll
    for (int j = 0; j < 8; ++j) acc[i][j] = 0.f;

  for (int kt = 0; kt < 4; ++kt) {
    int k0 = kt * 32;
    // stage t tile: thread -> row t>>1, seg t&1 (16 bf16)
    {
      int row = t >> 1, seg = t & 1;
      int gr = r0 + row;
      uint4 p0, p1;
      if (gr < NN) {
        const uint4* src = (const uint4*)(tb + gr * 64 + (k0 + seg * 16) / 2);
        p0 = src[0]; p1 = src[1];
      } else {
        p0 = make_uint4(0, 0, 0, 0); p1 = p0;
      }
      float* d = &t_lds[row * 36 + seg * 16];
      d[0] = bflo(p0.x); d[1] = bfhi(p0.x); d[2] = bflo(p0.y); d[3] = bfhi(p0.y);
      d[4] = bflo(p0.z); d[5] = bfhi(p0.z); d[6] = bflo(p0.w); d[7] = bfhi(p0.w);
      d[8] = bflo(p1.x); d[9] = bfhi(p1.x); d[10] = bflo(p1.y); d[11] = bfhi(p1.y);
      d[12] = bflo(p1.z); d[13] = bfhi(p1.z); d[14] = bflo(p1.w); d[15] = bfhi(p1.w);
    }
    // stage W0 tile: thread -> k row t>>3, 16 cols at (t&7)*16
    {
      int kk = t >> 3, cb = (t & 7) * 16;
      const float4* src = (const float4*)(W0 + (size_t)(k0 + kk) * D + cb);
      float4* dst = (float4*)(&w0_lds[kk * 128 + cb]);
#pragma unroll
      for (int j = 0; j < 4; ++j) dst[j] = src[j];
    }
    __syncthreads();

    for (int k4 = 0; k4 < 8; ++k4) {
      float4 b0[4], b1[4];
#pragma unroll
      for (int kk = 0; kk < 4; ++kk) {
        const float* wr = &w0_lds[(k4 * 4 + kk) * 128 + tc * 8];
        b0[kk] = *(const float4*)wr;
        b1[kk] = *(const float4*)(wr + 4);
      }
#pragma unroll
      for (int i = 0; i < 8; ++i) {
        float4 av = *(const float4*)&t_lds[(tr * 8 + i) * 36 + k4 * 4];
        float aw[4] = {av.x, av.y, av.z, av.w};
#pragma unroll
        for (int kk = 0; kk < 4; ++kk) {
          acc[i][0] += aw[kk] * b0[kk].x; acc[i][1] += aw[kk] * b0[kk].y;
          acc[i][2] += aw[kk] * b0[kk].z; acc[i][3] += aw[kk] * b0[kk].w;
          acc[i][4] += aw[kk] * b1[kk].x; acc[i][5] += aw[kk] * b1[kk].y;
          acc[i][6] += aw[kk] * b1[kk].z; acc[i][7] += aw[kk] * b1[kk].w;
        }
      }
    }
    __syncthreads();
  }

  // epilogue: per 32-row quarter, relu+mask -> LDS (stride USTRIDE), project to z
  int c  = t & 127, r8 = t >> 7;
  bool active = (c < ZC);
  bool isH = (c < DO1);
  const float* wp = isH ? (W1 + c) : (Wss + (c - DO1));
  int wstride = isH ? DO1 : DO2;

  for (int q = 0; q < 4; ++q) {
    if ((tr >> 2) == q) {
      int rl = (tr & 3) * 8;
#pragma unroll
      for (int i = 0; i < 8; ++i) {
        int gr = r0 + tr * 8 + i;
        float* d1 = &u1q[(rl + i) * USTRIDE + tc * 8];
        float* d2 = &u2q[(rl + i) * USTRIDE + tc * 8];
        if (gr < NN) {
          uint mw1 = m1[gr * 4 + (tc >> 2)];
          uint mw2 = m2[gr * 4 + (tc >> 2)];
          int bb = (tc & 3) * 8;
#pragma unroll
          for (int j = 0; j < 8; ++j) {
            float u = fmaxf(acc[i][j], 0.f) * 1.25f;
            d1[j] = ((mw1 >> (bb + j)) & 1u) ? u : 0.f;
            d2[j] = ((mw2 >> (bb + j)) & 1u) ? u : 0.f;
          }
        } else {
#pragma unroll
          for (int j = 0; j < 8; ++j) { d1[j] = 0.f; d2[j] = 0.f; }
        }
      }
    }
    __syncthreads();
    if (active) {
      const float* uq = isH ? u1q : u2q;
      float za[16];
#pragma unroll
      for (int ri = 0; ri < 16; ++ri) za[ri] = 0.f;
      for (int k4 = 0; k4 < 32; ++k4) {
        float wv[4];
#pragma unroll
        for (int kk = 0; kk < 4; ++kk) wv[kk] = wp[(k4 * 4 + kk) * wstride];
#pragma unroll
        for (int ri = 0; ri < 16; ++ri) {
          float4 uu = *(const float4*)&uq[(r8 + 2 * ri) * USTRIDE + k4 * 4];
          za[ri] += uu.x * wv[0] + uu.y * wv[1] + uu.z * wv[2] + uu.w * wv[3];
        }
      }
#pragma unroll
      for (int ri = 0; ri < 16; ++ri) {
        int gr = r0 + q * 32 + r8 + 2 * ri;
        if (gr < NN) zz[(size_t)gr * ZC + c] = (ushort)f2bf(za[ri]);
      }
    }
    __syncthreads();
  }
}

// ---------------- out = spmm(z): wave per row ----------------
__global__ void gather_out_kernel(const int* __restrict__ ptr, const int* __restrict__ col_s,
                                  const float* __restrict__ val_s, const uint* __restrict__ zp,
                                  float* __restrict__ out) {
  int r = blockIdx.x * 4 + (threadIdx.x >> 6);
  int lane = threadIdx.x & 63;
  if (lane >= 52) return;
  int s = ptr[r], e = ptr[r + 1];
  float ax = 0.f, ay = 0.f;
  for (int i = s; i < e; ++i) {
    int c = col_s[i];
    float v = val_s[i];
    uint p = zp[c * 52 + lane];
    ax += v * bflo(p);
    ay += v * bfhi(p);
  }
  if (lane < 20) {
    float2* d = (float2*)(out + (size_t)r * DO1 + 2 * lane);
    *d = make_float2(ax, ay);
  } else {
    float2* d = (float2*)(out + OUT_S_OFF + (size_t)r * DO2 + 2 * lane - DO1);
    *d = make_float2(ax, ay);
  }
}

// ---------------- launch ----------------
extern "C" void kernel_launch(void* const* d_in, const int* in_sizes, int n_in,
                              void* d_out, int out_size, void* d_ws, size_t ws_size,
                              hipStream_t stream) {
  const float* x       = (const float*)d_in[0];
  const int*   adj_row = (const int*)d_in[1];
  const int*   adj_col = (const int*)d_in[2];
  const float* adj_val = (const float*)d_in[3];
  const float* W0      = (const float*)d_in[4];
  const float* W1      = (const float*)d_in[5];
  const float* Wss     = (const float*)d_in[6];
  float* out = (float*)d_out;

  char* ws = (char*)d_ws;
  uint*   t_bf  = (uint*)(ws + 0);           // 25,600,000 B (bf16 t, as uints)
  uint*   xb    = (uint*)(ws + 25600000);    // 25,600,000 B (bf16 x; z aliases)
  ushort* zz    = (ushort*)(ws + 25600000);  // 20,800,000 B (bf16 z)
  uint*   m1    = (uint*)(ws + 51200000);    //  1,600,000 B
  uint*   m2    = (uint*)(ws + 52800000);    //  1,600,000 B
  int*    ptr   = (int*)(ws + 54400000);     //    400,004 B
  int*    cnt   = (int*)(ws + 54800004);     //    400,000 B
  int*    cur   = (int*)(ws + 55200004);     //    400,000 B (scan aux reuses)
  int*    col_s = (int*)(ws + 55600004);     //  6,400,000 B
  float*  val_s = (float*)(ws + 62000004);   //  6,400,000 B  (end 68,400,004)
  int*    aux   = cur;

  hipMemsetAsync(cnt, 0, NN * sizeof(int), stream);
  convx_kernel<<<25000, 256, 0, stream>>>(x, xb);
  mask_kernel<<<3125, 256, 0, stream>>>(m1, m2);
  hist_kernel<<<6250, 256, 0, stream>>>(adj_row, cnt);
  scan_reduce<<<98, 256, 0, stream>>>(cnt, aux);
  scan_aux<<<1, 128, 0, stream>>>(aux, ptr);
  scan_apply<<<98, 256, 0, stream>>>(cnt, aux, ptr);
  hipMemcpyAsync(cur, ptr, NN * sizeof(int), hipMemcpyDeviceToDevice, stream);
  scatter_kernel<<<6250, 256, 0, stream>>>(adj_row, adj_col, adj_val, cur, col_s, val_s);
  spmm_x_kernel<<<25000, 256, 0, stream>>>(ptr, col_s, val_s, xb, t_bf);
  pass_a_kernel<<<782, 256, 0, stream>>>(t_bf, W0, W1, Wss, m1, m2, zz);
  gather_out_kernel<<<25000, 256, 0, stream>>>(ptr, col_s, val_s, (const uint*)zz, out);
}

// Round 6
// 521.365 us; speedup vs baseline: 2.5655x; 1.4850x over previous
//
#include <hip/hip_runtime.h>
#include <stdint.h>

// net_gcn_multitask — MI355X. Pipeline (bf16 MFMA for dense, bf16 gathers):
//   xb = bf16(x); t = spmm(xb)                      [32-lane/row gather]
//   U = relu(t@W0) [MFMA]; z = [drop1(U)@W1 | drop2(U)@Wss] [MFMA, swapped]
//   h = spmm(z)[:, :40], s = spmm(z)[:, 40:]        [32-lane/row gather]
// CSR built on device (hist -> 3-phase scan -> scatter).

#define NN 100000
#define NE 1600000
#define D 128
#define NW 400000        // mask words per mask: NN*D/32
#define ZC 104
#define DO1 40
#define DO2 64
#define OUT_S_OFF 4000000
#define KEEP_THR 6710886u

typedef unsigned int uint;
typedef __attribute__((ext_vector_type(4))) float f32x4;
typedef __attribute__((ext_vector_type(8))) short short8;
union U4S8 { uint4 u; short8 s; };

// ---------------- bf16 helpers ----------------
__device__ __forceinline__ float bflo(uint p) { return __uint_as_float(p << 16); }
__device__ __forceinline__ float bfhi(uint p) { return __uint_as_float(p & 0xffff0000u); }
__device__ __forceinline__ uint f2bf(float f) {
  uint u = __float_as_uint(f);
  return (u + 0x7fffu + ((u >> 16) & 1u)) >> 16;   // RTNE
}
__device__ __forceinline__ uint pack2(float lo, float hi) {
  return f2bf(lo) | (f2bf(hi) << 16);
}

// ---------------- threefry2x32 (JAX partitionable; verified) ----------------
__device__ __forceinline__ void tf2x32(uint k0, uint k1, uint x0, uint x1,
                                       uint& o0, uint& o1) {
  uint ks2 = k0 ^ k1 ^ 0x1BD11BDAu;
  x0 += k0; x1 += k1;
#define TFR(r) { x0 += x1; x1 = (x1 << (r)) | (x1 >> (32 - (r))); x1 ^= x0; }
  TFR(13) TFR(15) TFR(26) TFR(6)
  x0 += k1;  x1 += ks2 + 1u;
  TFR(17) TFR(29) TFR(16) TFR(24)
  x0 += ks2; x1 += k0 + 2u;
  TFR(13) TFR(15) TFR(26) TFR(6)
  x0 += k0;  x1 += k1 + 3u;
  TFR(17) TFR(29) TFR(16) TFR(24)
  x0 += k1;  x1 += ks2 + 4u;
  TFR(13) TFR(15) TFR(26) TFR(6)
  x0 += ks2; x1 += k0 + 5u;
#undef TFR
  o0 = x0; o1 = x1;
}

__global__ void mask_kernel(uint* __restrict__ m1, uint* __restrict__ m2) {
  int t = blockIdx.x * blockDim.x + threadIdx.x;
  if (t >= 2 * NW) return;
  uint a0, a1, b0, b1;
  tf2x32(0u, 42u, 0u, 0u, a0, a1);
  tf2x32(0u, 42u, 0u, 1u, b0, b1);
  bool second = (t >= NW);
  uint w  = second ? (uint)(t - NW) : (uint)t;
  uint k0 = second ? b0 : a0;
  uint k1 = second ? b1 : a1;
  uint base = w * 32u;
  uint word = 0u;
  for (int i = 0; i < 32; ++i) {
    uint o0, o1;
    tf2x32(k0, k1, 0u, base + (uint)i, o0, o1);
    word |= (uint)(((o0 ^ o1) >> 9) <= KEEP_THR) << i;
  }
  (second ? m2 : m1)[w] = word;
}

// ---------------- x -> bf16 ----------------
__global__ void convx_kernel(const float* __restrict__ x, uint* __restrict__ xb) {
  int i = blockIdx.x * blockDim.x + threadIdx.x;
  float2 v = ((const float2*)x)[i];
  xb[i] = pack2(v.x, v.y);
}

// ---------------- weight prep: transposed bf16 ----------------
__global__ void prep_w0t(const float* __restrict__ W0, ushort* __restrict__ w0t) {
  int idx = blockIdx.x * blockDim.x + threadIdx.x;   // 16384
  int c = idx >> 7, k = idx & 127;
  w0t[idx] = (ushort)f2bf(W0[k * D + c]);
}
__global__ void prep_wcat(const float* __restrict__ W1, const float* __restrict__ Wss,
                          ushort* __restrict__ wcatT) {
  int idx = blockIdx.x * blockDim.x + threadIdx.x;   // 14336
  int c = idx >> 7, k = idx & 127;
  float v = (c < 40) ? W1[k * DO1 + c] : ((c < 48) ? 0.f : Wss[k * DO2 + (c - 48)]);
  wcatT[idx] = (ushort)f2bf(v);
}

// ---------------- CSR build ----------------
__global__ void hist_kernel(const int* __restrict__ row, int* __restrict__ cnt) {
  int e = blockIdx.x * blockDim.x + threadIdx.x;
  if (e < NE) atomicAdd(&cnt[row[e]], 1);
}

__global__ void scan_reduce(const int* __restrict__ cnt, int* __restrict__ aux) {
  __shared__ int sb[256];
  int b = blockIdx.x, t = threadIdx.x;
  int base = b * 1024 + t * 4, s = 0;
#pragma unroll
  for (int j = 0; j < 4; ++j) { int i = base + j; s += (i < NN) ? cnt[i] : 0; }
  sb[t] = s; __syncthreads();
  for (int off = 128; off > 0; off >>= 1) {
    if (t < off) sb[t] += sb[t + off];
    __syncthreads();
  }
  if (t == 0) aux[b] = sb[0];
}

__global__ void scan_aux(int* __restrict__ aux, int* __restrict__ ptr) {
  __shared__ int sb[128];
  int t = threadIdx.x;
  int v = (t < 98) ? aux[t] : 0;
  sb[t] = v; __syncthreads();
  for (int off = 1; off < 128; off <<= 1) {
    int a = (t >= off) ? sb[t - off] : 0;
    __syncthreads();
    sb[t] += a;
    __syncthreads();
  }
  if (t < 98) aux[t] = sb[t] - v;
  if (t == 127) ptr[NN] = sb[127];
}

__global__ void scan_apply(const int* __restrict__ cnt, const int* __restrict__ aux,
                           int* __restrict__ ptr) {
  __shared__ int sb[256];
  int b = blockIdx.x, t = threadIdx.x;
  int base = b * 1024 + t * 4;
  int c[4], ts = 0;
#pragma unroll
  for (int j = 0; j < 4; ++j) { int i = base + j; c[j] = (i < NN) ? cnt[i] : 0; ts += c[j]; }
  sb[t] = ts; __syncthreads();
  for (int off = 1; off < 256; off <<= 1) {
    int a = (t >= off) ? sb[t - off] : 0;
    __syncthreads();
    sb[t] += a;
    __syncthreads();
  }
  int off0 = aux[b] + sb[t] - ts;
#pragma unroll
  for (int j = 0; j < 4; ++j) {
    int i = base + j;
    if (i < NN) ptr[i] = off0;
    off0 += c[j];
  }
}

__global__ void scatter_kernel(const int* __restrict__ row, const int* __restrict__ col,
                               const float* __restrict__ val, int* __restrict__ cursor,
                               int* __restrict__ col_s, float* __restrict__ val_s) {
  int e = blockIdx.x * blockDim.x + threadIdx.x;
  if (e < NE) {
    int r = row[e];
    int p = atomicAdd(&cursor[r], 1);
    col_s[p] = col[e];
    val_s[p] = val[e];
  }
}

// ---------------- t = spmm(xb): 32 lanes per row, uint2 (8B) per lane -----
__global__ void spmm_x_kernel(const int* __restrict__ ptr, const int* __restrict__ col_s,
                              const float* __restrict__ val_s, const uint2* __restrict__ xb,
                              uint2* __restrict__ t) {
  int r = blockIdx.x * 8 + (threadIdx.x >> 5);
  int k = threadIdx.x & 31;
  int s = ptr[r], e = ptr[r + 1];
  float a0 = 0.f, a1 = 0.f, a2 = 0.f, a3 = 0.f;
  for (int i = s; i < e; ++i) {
    int c = col_s[i];
    float v = val_s[i];
    uint2 p = xb[c * 32 + k];
    a0 += v * bflo(p.x); a1 += v * bfhi(p.x);
    a2 += v * bflo(p.y); a3 += v * bfhi(p.y);
  }
  t[r * 32 + k] = make_uint2(pack2(a0, a1), pack2(a2, a3));
}

// ---- pass A (MFMA): U = relu(T@W0); Z^T = Wcat^T @ U^T (dropout-masked) ----
// 512 thr (8 waves), 128-row tile. LDS: T(32K)+W0T(32K)+masks(4K); U1/U2 reuse.
#define SWZ(row, byte) ((row) * 256 + ((byte) ^ ((((row) >> 1) & 7) << 4)))
__global__ __launch_bounds__(512, 4) void pass_a_kernel(
    const uint* __restrict__ tb, const ushort* __restrict__ w0t,
    const ushort* __restrict__ wcatT,
    const uint* __restrict__ m1, const uint* __restrict__ m2,
    ushort* __restrict__ zz) {
  __shared__ __align__(16) char ldsb[69632];
  uint* mlds = (uint*)(ldsb + 65536);          // [2][128][4]

  int t = threadIdx.x;
  int r0 = blockIdx.x * 128;
  int wid = t >> 6, l = t & 63, lc = l & 15, lk = l >> 4;

  // stage T (bf16, swizzled) and W0T
#pragma unroll
  for (int i = 0; i < 4; ++i) {
    int lin = i * 512 + t;            // 0..2047
    int row = lin >> 4, seg = lin & 15;
    int gr = r0 + row;
    uint4 v = make_uint4(0, 0, 0, 0);
    if (gr < NN) v = ((const uint4*)(tb + (size_t)gr * 64))[seg];
    *(uint4*)&ldsb[SWZ(row, seg * 16)] = v;
    uint4 w = ((const uint4*)w0t)[lin];
    *(uint4*)&ldsb[32768 + SWZ(row, seg * 16)] = w;
  }
  // stage masks: [m][row][word]
#pragma unroll
  for (int i = 0; i < 2; ++i) {
    int idx = t;                       // 0..511
    int row = idx >> 2, word = idx & 3;
    int gr = r0 + row;
    uint v = 0;
    if (gr < NN) v = (i == 0 ? m1 : m2)[gr * 4 + word];
    mlds[i * 512 + idx] = v;
  }
  __syncthreads();

  // stage 1: U tile rows [16*wid, 16*wid+16), cols 0..127
  short8 af[4];
#pragma unroll
  for (int s = 0; s < 4; ++s) {
    U4S8 tmp; tmp.u = *(uint4*)&ldsb[SWZ(16 * wid + lc, 64 * s + 16 * lk)];
    af[s] = tmp.s;
  }
  f32x4 acc[8];
#pragma unroll
  for (int n = 0; n < 8; ++n) acc[n] = (f32x4)(0.f);
#pragma unroll
  for (int n = 0; n < 8; ++n) {
#pragma unroll
    for (int s = 0; s < 4; ++s) {
      U4S8 tmp; tmp.u = *(uint4*)&ldsb[32768 + SWZ(16 * n + lc, 64 * s + 16 * lk)];
      acc[n] = __builtin_amdgcn_mfma_f32_16x16x32_bf16(af[s], tmp.s, acc[n], 0, 0, 0);
    }
  }
  __syncthreads();   // all T/W0T reads done; reuse LDS for U1/U2

  // epilogue: relu * 1.25, masks -> U1 (base 0), U2 (base 32768), bf16 swizzled
#pragma unroll
  for (int reg = 0; reg < 4; ++reg) {
    int row = 16 * wid + 4 * lk + reg;
    uint4 w1q = *(uint4*)&mlds[row * 4];
    uint4 w2q = *(uint4*)&mlds[512 + row * 4];
    uint w1a[4] = {w1q.x, w1q.y, w1q.z, w1q.w};
    uint w2a[4] = {w2q.x, w2q.y, w2q.z, w2q.w};
#pragma unroll
    for (int n = 0; n < 8; ++n) {
      float v = fmaxf(acc[n][reg], 0.f) * 1.25f;
      ushort ub = (ushort)f2bf(v);
      int bit = (n & 1) * 16 + lc;
      ushort u1 = ((w1a[n >> 1] >> bit) & 1u) ? ub : (ushort)0;
      ushort u2 = ((w2a[n >> 1] >> bit) & 1u) ? ub : (ushort)0;
      int ad = SWZ(row, 32 * n + 2 * lc);
      *(ushort*)&ldsb[ad] = u1;
      *(ushort*)&ldsb[32768 + ad] = u2;
    }
  }
  __syncthreads();

  // stage 2: Z^T tiles: A = wcatT (global, L2), B = U1/U2 (LDS)
  f32x4 acc2[7];
#pragma unroll
  for (int n = 0; n < 7; ++n) acc2[n] = (f32x4)(0.f);
#pragma unroll
  for (int n2 = 0; n2 < 7; ++n2) {
    int ubase = (n2 < 3) ? 0 : 32768;
#pragma unroll
    for (int s = 0; s < 4; ++s) {
      // wcatT row = 16*n2+lc, 128 ushorts/row = 16 uint4/row
      U4S8 a2; a2.u = ((const uint4*)wcatT)[(16 * n2 + lc) * 16 + 4 * s + lk];
      U4S8 b2; b2.u = *(uint4*)&ldsb[ubase + SWZ(16 * wid + lc, 64 * s + 16 * lk)];
      acc2[n2] = __builtin_amdgcn_mfma_f32_16x16x32_bf16(a2.s, b2.s, acc2[n2], 0, 0, 0);
    }
  }

  // store z: lane holds z-cols [cb, cb+4) for node row r0+16*wid+lc
  int r = r0 + 16 * wid + lc;
  if (r < NN) {
#pragma unroll
    for (int n2 = 0; n2 < 7; ++n2) {
      if (n2 == 2 && lk >= 2) continue;          // W1 pad cols 40..47
      int cb = 16 * n2 + 4 * lk;
      if (n2 >= 3) cb -= 8;
      uint2 v = make_uint2(pack2(acc2[n2][0], acc2[n2][1]),
                           pack2(acc2[n2][2], acc2[n2][3]));
      *(uint2*)(zz + (size_t)r * ZC + cb) = v;
    }
  }
}

// ---------------- out = spmm(z): 32 lanes per row, uint2 per lane ----------
__global__ void gather_out_kernel(const int* __restrict__ ptr, const int* __restrict__ col_s,
                                  const float* __restrict__ val_s, const uint2* __restrict__ zp,
                                  float* __restrict__ out) {
  int r = blockIdx.x * 8 + (threadIdx.x >> 5);
  int k = threadIdx.x & 31;
  int kk = (k < 26) ? k : 25;
  int s = ptr[r], e = ptr[r + 1];
  float a0 = 0.f, a1 = 0.f, a2 = 0.f, a3 = 0.f;
  for (int i = s; i < e; ++i) {
    int c = col_s[i];
    float v = val_s[i];
    uint2 p = zp[c * 26 + kk];
    a0 += v * bflo(p.x); a1 += v * bfhi(p.x);
    a2 += v * bflo(p.y); a3 += v * bfhi(p.y);
  }
  if (k < 10) {
    *(float4*)(out + (size_t)r * DO1 + 4 * k) = make_float4(a0, a1, a2, a3);
  } else if (k < 26) {
    *(float4*)(out + OUT_S_OFF + (size_t)r * DO2 + 4 * (k - 10)) = make_float4(a0, a1, a2, a3);
  }
}

// ---------------- launch ----------------
extern "C" void kernel_launch(void* const* d_in, const int* in_sizes, int n_in,
                              void* d_out, int out_size, void* d_ws, size_t ws_size,
                              hipStream_t stream) {
  const float* x       = (const float*)d_in[0];
  const int*   adj_row = (const int*)d_in[1];
  const int*   adj_col = (const int*)d_in[2];
  const float* adj_val = (const float*)d_in[3];
  const float* W0      = (const float*)d_in[4];
  const float* W1      = (const float*)d_in[5];
  const float* Wss     = (const float*)d_in[6];
  float* out = (float*)d_out;

  char* ws = (char*)d_ws;
  uint*   t_bf  = (uint*)(ws + 0);           // 25,600,000 B bf16 t
  uint*   xb    = (uint*)(ws + 25600000);    // 25,600,000 B bf16 x (z aliases)
  ushort* zz    = (ushort*)(ws + 25600000);  // 20,800,000 B bf16 z
  uint*   m1    = (uint*)(ws + 51200000);    //  1,600,000 B
  uint*   m2    = (uint*)(ws + 52800000);    //  1,600,000 B
  int*    ptr   = (int*)(ws + 54400000);     //    400,004 B
  int*    cnt   = (int*)(ws + 54800004);     //    400,000 B (w prep reuses)
  int*    cur   = (int*)(ws + 55200004);     //    400,000 B (scan aux reuses)
  int*    col_s = (int*)(ws + 55600004);     //  6,400,000 B
  float*  val_s = (float*)(ws + 62000004);   //  6,400,000 B (end 68,400,004)
  int*    aux   = cur;
  ushort* w0t   = (ushort*)(ws + 54800016);  // 32,768 B (in dead cnt region)
  ushort* wcatT = (ushort*)(ws + 54832784);  // 28,672 B

  hipMemsetAsync(cnt, 0, NN * sizeof(int), stream);
  convx_kernel<<<25000, 256, 0, stream>>>(x, xb);
  mask_kernel<<<3125, 256, 0, stream>>>(m1, m2);
  hist_kernel<<<6250, 256, 0, stream>>>(adj_row, cnt);
  scan_reduce<<<98, 256, 0, stream>>>(cnt, aux);
  scan_aux<<<1, 128, 0, stream>>>(aux, ptr);
  scan_apply<<<98, 256, 0, stream>>>(cnt, aux, ptr);
  hipMemcpyAsync(cur, ptr, NN * sizeof(int), hipMemcpyDeviceToDevice, stream);
  scatter_kernel<<<6250, 256, 0, stream>>>(adj_row, adj_col, adj_val, cur, col_s, val_s);
  spmm_x_kernel<<<12500, 256, 0, stream>>>(ptr, col_s, val_s, (const uint2*)xb, (uint2*)t_bf);
  prep_w0t<<<64, 256, 0, stream>>>(W0, w0t);           // cnt dead from here
  prep_wcat<<<56, 256, 0, stream>>>(W1, Wss, wcatT);
  pass_a_kernel<<<782, 512, 0, stream>>>(t_bf, w0t, wcatT, m1, m2, zz);
  gather_out_kernel<<<12500, 256, 0, stream>>>(ptr, col_s, val_s, (const uint2*)zz, out);
}

// Round 7
// 377.443 us; speedup vs baseline: 3.5437x; 1.3813x over previous
//
#include <hip/hip_runtime.h>
#include <stdint.h>

// net_gcn_multitask — MI355X.
//   prep: xb=bf16(x), masks (threefry), w0t/wcatT bf16, bucket cursors
//   bin:  edges -> 49 row-buckets (8B entries, burst writes)
//   csr:  per-bucket (1 block/bucket): row hist -> LDS scan -> ptr + cv[(col,val)]
//   spmm_x: t = spmm(xb)              [32-lane/row gather]
//   pass_a: U=relu(t@W0) [MFMA]; z=[drop1(U)@W1 | drop2(U)@Wss] [MFMA]
//   gather_out: h|s = spmm(z)         [32-lane/row gather]

#define NN 100000
#define NE 1600000
#define D 128
#define NW 400000
#define ZC 104
#define DO1 40
#define DO2 64
#define OUT_S_OFF 4000000
#define KEEP_THR 6710886u
#define NB 49          // buckets of 2048 rows
#define CAP 36000      // entries per bucket region (mean 32653, ~18 sigma)
#define MASKB 3125
#define CONVB 25000

typedef unsigned int uint;
typedef __attribute__((ext_vector_type(4))) float f32x4;
typedef __attribute__((ext_vector_type(8))) short short8;
union U4S8 { uint4 u; short8 s; };

// ---------------- bf16 helpers ----------------
__device__ __forceinline__ float bflo(uint p) { return __uint_as_float(p << 16); }
__device__ __forceinline__ float bfhi(uint p) { return __uint_as_float(p & 0xffff0000u); }
__device__ __forceinline__ uint f2bf(float f) {
  uint u = __float_as_uint(f);
  return (u + 0x7fffu + ((u >> 16) & 1u)) >> 16;   // RTNE
}
__device__ __forceinline__ uint pack2(float lo, float hi) {
  return f2bf(lo) | (f2bf(hi) << 16);
}

// ---------------- threefry2x32 (JAX partitionable; verified) --------------
__device__ __forceinline__ void tf2x32(uint k0, uint k1, uint x0, uint x1,
                                       uint& o0, uint& o1) {
  uint ks2 = k0 ^ k1 ^ 0x1BD11BDAu;
  x0 += k0; x1 += k1;
#define TFR(r) { x0 += x1; x1 = (x1 << (r)) | (x1 >> (32 - (r))); x1 ^= x0; }
  TFR(13) TFR(15) TFR(26) TFR(6)
  x0 += k1;  x1 += ks2 + 1u;
  TFR(17) TFR(29) TFR(16) TFR(24)
  x0 += ks2; x1 += k0 + 2u;
  TFR(13) TFR(15) TFR(26) TFR(6)
  x0 += k0;  x1 += k1 + 3u;
  TFR(17) TFR(29) TFR(16) TFR(24)
  x0 += k1;  x1 += ks2 + 4u;
  TFR(13) TFR(15) TFR(26) TFR(6)
  x0 += ks2; x1 += k0 + 5u;
#undef TFR
  o0 = x0; o1 = x1;
}

// ---- fused prep: convx | masks | weight transpose | cursor init ----------
__global__ void prep_kernel(const float* __restrict__ x, uint* __restrict__ xb,
                            uint* __restrict__ m1, uint* __restrict__ m2,
                            const float* __restrict__ W0, const float* __restrict__ W1,
                            const float* __restrict__ Wss,
                            ushort* __restrict__ w0t, ushort* __restrict__ wcatT,
                            int* __restrict__ cursor) {
  int bid = blockIdx.x, tid = threadIdx.x;
  if (bid < CONVB) {
    if (bid == 0 && tid < NB) cursor[tid] = tid * CAP;
    int i = bid * 256 + tid;
    float2 v = ((const float2*)x)[i];
    xb[i] = pack2(v.x, v.y);
  } else if (bid < CONVB + MASKB) {
    int t = (bid - CONVB) * 256 + tid;
    uint a0, a1, b0, b1;
    tf2x32(0u, 42u, 0u, 0u, a0, a1);
    tf2x32(0u, 42u, 0u, 1u, b0, b1);
    bool second = (t >= NW);
    uint w  = second ? (uint)(t - NW) : (uint)t;
    uint k0 = second ? b0 : a0;
    uint k1 = second ? b1 : a1;
    uint base = w * 32u;
    uint word = 0u;
    for (int i = 0; i < 32; ++i) {
      uint o0, o1;
      tf2x32(k0, k1, 0u, base + (uint)i, o0, o1);
      word |= (uint)(((o0 ^ o1) >> 9) <= KEEP_THR) << i;
    }
    (second ? m2 : m1)[w] = word;
  } else {
    int idx = (bid - CONVB - MASKB) * 256 + tid;   // 0..30719
    if (idx < 16384) {
      int c = idx >> 7, k = idx & 127;
      w0t[idx] = (ushort)f2bf(W0[k * D + c]);
    } else {
      int j = idx - 16384;                         // 0..14335
      int c = j >> 7, k = j & 127;
      float v = (c < 40) ? W1[k * DO1 + c] : ((c < 48) ? 0.f : Wss[k * DO2 + (c - 48)]);
      wcatT[j] = (ushort)f2bf(v);
    }
  }
}

// ---- bin: edges -> buckets; entry = (row_local<<17 | col, val_bits) -------
__global__ void bin_kernel(const int* __restrict__ row, const int* __restrict__ col,
                           const float* __restrict__ val, int* __restrict__ cursor,
                           uint2* __restrict__ buck) {
  __shared__ int h[NB];
  __shared__ int base[NB];
  int tid = threadIdx.x;
  if (tid < NB) h[tid] = 0;
  __syncthreads();
  int e0 = blockIdx.x * 8192;
#pragma unroll 4
  for (int j = 0; j < 32; ++j) {
    int e = e0 + j * 256 + tid;
    if (e < NE) atomicAdd(&h[row[e] >> 11], 1);
  }
  __syncthreads();
  if (tid < NB) {
    int c = h[tid];
    base[tid] = c ? atomicAdd(&cursor[tid], c) : 0;
    h[tid] = 0;
  }
  __syncthreads();
#pragma unroll 4
  for (int j = 0; j < 32; ++j) {
    int e = e0 + j * 256 + tid;
    if (e < NE) {
      int r = row[e];
      int b = r >> 11;
      int k = atomicAdd(&h[b], 1);
      int idx = base[b] + k;
      int lim = (b + 1) * CAP;
      if (idx >= lim) idx = lim - 1;   // overflow guard (never at 18 sigma)
      buck[idx] = make_uint2(((uint)(r & 2047) << 17) | (uint)col[e],
                             __float_as_uint(val[e]));
    }
  }
}

// ---- csr: one block per bucket -> ptr + interleaved cv (localized writes) -
__global__ __launch_bounds__(1024) void csr_kernel(const uint2* __restrict__ buck,
                                                   const int* __restrict__ cursor,
                                                   int* __restrict__ ptr,
                                                   uint2* __restrict__ cv) {
  __shared__ int cnt[2048];
  __shared__ int sc[2048];
  __shared__ int cb[NB];
  int b = blockIdx.x, tid = threadIdx.x;
  if (tid < NB) cb[tid] = min(cursor[tid] - tid * CAP, CAP);
  int i0 = tid, i1 = tid + 1024;
  cnt[i0] = 0; cnt[i1] = 0;
  __syncthreads();
  int gbase = 0;
  for (int i = 0; i < b; ++i) gbase += cb[i];
  int n = cb[b];
  int src = b * CAP;
  for (int i = tid; i < n; i += 1024) atomicAdd(&cnt[buck[src + i].x >> 17], 1);
  __syncthreads();
  sc[i0] = cnt[i0]; sc[i1] = cnt[i1];
  __syncthreads();
  for (int off = 1; off < 2048; off <<= 1) {
    int v0 = (i0 >= off) ? sc[i0 - off] : 0;
    int v1 = (i1 >= off) ? sc[i1 - off] : 0;
    __syncthreads();
    sc[i0] += v0; sc[i1] += v1;
    __syncthreads();
  }
  int r0 = b * 2048;
  int s0 = sc[i0] - cnt[i0], s1 = sc[i1] - cnt[i1];
  if (r0 + i0 < NN) ptr[r0 + i0] = gbase + s0;
  if (r0 + i1 < NN) ptr[r0 + i1] = gbase + s1;
  if (b == 0 && tid == 0) ptr[NN] = NE;
  cnt[i0] = s0; cnt[i1] = s1;
  __syncthreads();
  for (int i = tid; i < n; i += 1024) {
    uint2 e = buck[src + i];
    int rl = e.x >> 17;
    int k = atomicAdd(&cnt[rl], 1);
    cv[gbase + k] = make_uint2(e.x & 0x1FFFFu, e.y);
  }
}

// ---------------- t = spmm(xb): 32 lanes per row, uint2 per lane ----------
__global__ void spmm_x_kernel(const int* __restrict__ ptr, const uint2* __restrict__ cv,
                              const uint2* __restrict__ xb, uint2* __restrict__ t) {
  int r = blockIdx.x * 8 + (threadIdx.x >> 5);
  int k = threadIdx.x & 31;
  int s = ptr[r], e = ptr[r + 1];
  float a0 = 0.f, a1 = 0.f, a2 = 0.f, a3 = 0.f;
  for (int i = s; i < e; ++i) {
    uint2 ev = cv[i];
    float v = __uint_as_float(ev.y);
    uint2 p = xb[ev.x * 32 + k];
    a0 += v * bflo(p.x); a1 += v * bfhi(p.x);
    a2 += v * bflo(p.y); a3 += v * bfhi(p.y);
  }
  t[r * 32 + k] = make_uint2(pack2(a0, a1), pack2(a2, a3));
}

// ---- pass A (MFMA): U = relu(T@W0); Z^T = Wcat^T @ U^T (dropout-masked) ----
#define SWZ(row, byte) ((row) * 256 + ((byte) ^ ((((row) >> 1) & 7) << 4)))
__global__ __launch_bounds__(512, 4) void pass_a_kernel(
    const uint* __restrict__ tb, const ushort* __restrict__ w0t,
    const ushort* __restrict__ wcatT,
    const uint* __restrict__ m1, const uint* __restrict__ m2,
    ushort* __restrict__ zz) {
  __shared__ __align__(16) char ldsb[69632];
  uint* mlds = (uint*)(ldsb + 65536);          // [2][128][4]

  int t = threadIdx.x;
  int r0 = blockIdx.x * 128;
  int wid = t >> 6, l = t & 63, lc = l & 15, lk = l >> 4;

#pragma unroll
  for (int i = 0; i < 4; ++i) {
    int lin = i * 512 + t;            // 0..2047
    int row = lin >> 4, seg = lin & 15;
    int gr = r0 + row;
    uint4 v = make_uint4(0, 0, 0, 0);
    if (gr < NN) v = ((const uint4*)(tb + (size_t)gr * 64))[seg];
    *(uint4*)&ldsb[SWZ(row, seg * 16)] = v;
    uint4 w = ((const uint4*)w0t)[lin];
    *(uint4*)&ldsb[32768 + SWZ(row, seg * 16)] = w;
  }
#pragma unroll
  for (int i = 0; i < 2; ++i) {
    int idx = t;
    int row = idx >> 2, word = idx & 3;
    int gr = r0 + row;
    uint v = 0;
    if (gr < NN) v = (i == 0 ? m1 : m2)[gr * 4 + word];
    mlds[i * 512 + idx] = v;
  }
  __syncthreads();

  short8 af[4];
#pragma unroll
  for (int s = 0; s < 4; ++s) {
    U4S8 tmp; tmp.u = *(uint4*)&ldsb[SWZ(16 * wid + lc, 64 * s + 16 * lk)];
    af[s] = tmp.s;
  }
  f32x4 acc[8];
#pragma unroll
  for (int n = 0; n < 8; ++n) acc[n] = (f32x4)(0.f);
#pragma unroll
  for (int n = 0; n < 8; ++n) {
#pragma unroll
    for (int s = 0; s < 4; ++s) {
      U4S8 tmp; tmp.u = *(uint4*)&ldsb[32768 + SWZ(16 * n + lc, 64 * s + 16 * lk)];
      acc[n] = __builtin_amdgcn_mfma_f32_16x16x32_bf16(af[s], tmp.s, acc[n], 0, 0, 0);
    }
  }
  __syncthreads();

#pragma unroll
  for (int reg = 0; reg < 4; ++reg) {
    int row = 16 * wid + 4 * lk + reg;
    uint4 w1q = *(uint4*)&mlds[row * 4];
    uint4 w2q = *(uint4*)&mlds[512 + row * 4];
    uint w1a[4] = {w1q.x, w1q.y, w1q.z, w1q.w};
    uint w2a[4] = {w2q.x, w2q.y, w2q.z, w2q.w};
#pragma unroll
    for (int n = 0; n < 8; ++n) {
      float v = fmaxf(acc[n][reg], 0.f) * 1.25f;
      ushort ub = (ushort)f2bf(v);
      int bit = (n & 1) * 16 + lc;
      ushort u1 = ((w1a[n >> 1] >> bit) & 1u) ? ub : (ushort)0;
      ushort u2 = ((w2a[n >> 1] >> bit) & 1u) ? ub : (ushort)0;
      int ad = SWZ(row, 32 * n + 2 * lc);
      *(ushort*)&ldsb[ad] = u1;
      *(ushort*)&ldsb[32768 + ad] = u2;
    }
  }
  __syncthreads();

  f32x4 acc2[7];
#pragma unroll
  for (int n = 0; n < 7; ++n) acc2[n] = (f32x4)(0.f);
#pragma unroll
  for (int n2 = 0; n2 < 7; ++n2) {
    int ubase = (n2 < 3) ? 0 : 32768;
#pragma unroll
    for (int s = 0; s < 4; ++s) {
      U4S8 a2; a2.u = ((const uint4*)wcatT)[(16 * n2 + lc) * 16 + 4 * s + lk];
      U4S8 b2; b2.u = *(uint4*)&ldsb[ubase + SWZ(16 * wid + lc, 64 * s + 16 * lk)];
      acc2[n2] = __builtin_amdgcn_mfma_f32_16x16x32_bf16(a2.s, b2.s, acc2[n2], 0, 0, 0);
    }
  }

  int r = r0 + 16 * wid + lc;
  if (r < NN) {
#pragma unroll
    for (int n2 = 0; n2 < 7; ++n2) {
      if (n2 == 2 && lk >= 2) continue;          // W1 pad cols 40..47
      int cb = 16 * n2 + 4 * lk;
      if (n2 >= 3) cb -= 8;
      uint2 v = make_uint2(pack2(acc2[n2][0], acc2[n2][1]),
                           pack2(acc2[n2][2], acc2[n2][3]));
      *(uint2*)(zz + (size_t)r * ZC + cb) = v;
    }
  }
}

// ---------------- out = spmm(z): 32 lanes per row ----------
__global__ void gather_out_kernel(const int* __restrict__ ptr, const uint2* __restrict__ cv,
                                  const uint2* __restrict__ zp, float* __restrict__ out) {
  int r = blockIdx.x * 8 + (threadIdx.x >> 5);
  int k = threadIdx.x & 31;
  if (k >= 26) return;
  int s = ptr[r], e = ptr[r + 1];
  float a0 = 0.f, a1 = 0.f, a2 = 0.f, a3 = 0.f;
  for (int i = s; i < e; ++i) {
    uint2 ev = cv[i];
    float v = __uint_as_float(ev.y);
    uint2 p = zp[ev.x * 26 + k];
    a0 += v * bflo(p.x); a1 += v * bfhi(p.x);
    a2 += v * bflo(p.y); a3 += v * bfhi(p.y);
  }
  if (k < 10) {
    *(float4*)(out + (size_t)r * DO1 + 4 * k) = make_float4(a0, a1, a2, a3);
  } else {
    *(float4*)(out + OUT_S_OFF + (size_t)r * DO2 + 4 * (k - 10)) = make_float4(a0, a1, a2, a3);
  }
}

// ---------------- launch ----------------
extern "C" void kernel_launch(void* const* d_in, const int* in_sizes, int n_in,
                              void* d_out, int out_size, void* d_ws, size_t ws_size,
                              hipStream_t stream) {
  const float* x       = (const float*)d_in[0];
  const int*   adj_row = (const int*)d_in[1];
  const int*   adj_col = (const int*)d_in[2];
  const float* adj_val = (const float*)d_in[3];
  const float* W0      = (const float*)d_in[4];
  const float* W1      = (const float*)d_in[5];
  const float* Wss     = (const float*)d_in[6];
  float* out = (float*)d_out;

  char* ws = (char*)d_ws;
  uint*   t_bf  = (uint*)(ws + 0);           // 25,600,000 B bf16 t
  uint2*  buck  = (uint2*)(ws + 0);          // 14,112,000 B (aliases t_bf; dead before spmm_x)
  uint*   xb    = (uint*)(ws + 25600000);    // 25,600,000 B bf16 x
  ushort* zz    = (ushort*)(ws + 25600000);  // 20,800,000 B bf16 z (aliases xb; xb dead)
  uint*   m1    = (uint*)(ws + 51200000);    //  1,600,000 B
  uint*   m2    = (uint*)(ws + 52800000);    //  1,600,000 B
  int*    ptr   = (int*)(ws + 54400000);     //    400,004 B
  ushort* w0t   = (ushort*)(ws + 54800016);  //     32,768 B
  ushort* wcatT = (ushort*)(ws + 54832784);  //     28,672 B
  int*    curs  = (int*)(ws + 54861456);     //        196 B
  uint2*  cv    = (uint2*)(ws + 55600016);   // 12,800,000 B (end 68,400,016)

  prep_kernel<<<CONVB + MASKB + 120, 256, 0, stream>>>(x, xb, m1, m2, W0, W1, Wss,
                                                       w0t, wcatT, curs);
  bin_kernel<<<196, 256, 0, stream>>>(adj_row, adj_col, adj_val, curs, buck);
  csr_kernel<<<NB, 1024, 0, stream>>>(buck, curs, ptr, cv);
  spmm_x_kernel<<<12500, 256, 0, stream>>>(ptr, cv, (const uint2*)xb, (uint2*)t_bf);
  pass_a_kernel<<<782, 512, 0, stream>>>(t_bf, w0t, wcatT, m1, m2, zz);
  gather_out_kernel<<<12500, 256, 0, stream>>>(ptr, cv, (const uint2*)zz, out);
}

// Round 8
// 308.938 us; speedup vs baseline: 4.3295x; 1.2217x over previous
//
#include <hip/hip_runtime.h>
#include <stdint.h>

// net_gcn_multitask — MI355X.
//   prep: xb=bf16(x), masks (threefry), w0t/wcatT bf16, bucket cursors
//   bin:  edges -> 49 row-buckets (8B entries, burst writes)
//   csr:  per-bucket (1 block/bucket): row hist -> LDS scan -> ptr + cv[(col,val)]
//   spmm_x: t = spmm(xb)              [32-lane/row gather, 4x unrolled]
//   pass_a: U=relu(t@W0) [MFMA]; z=[drop1(U)@W1 | drop2(U)@Wss] [MFMA]
//   gather_out: h|s = spmm(z)         [32-lane/row gather, 4x unrolled]

#define NN 100000
#define NE 1600000
#define D 128
#define NW 400000
#define ZC 104
#define DO1 40
#define DO2 64
#define OUT_S_OFF 4000000
#define KEEP_THR 6710886u
#define NB 49          // buckets of 2048 rows
#define CAP 36000      // entries per bucket region (mean 32653, ~18 sigma)
#define MASKB 3125
#define CONVB 25000

typedef unsigned int uint;
typedef __attribute__((ext_vector_type(4))) float f32x4;
typedef __attribute__((ext_vector_type(8))) short short8;
union U4S8 { uint4 u; short8 s; };

// ---------------- bf16 helpers ----------------
__device__ __forceinline__ float bflo(uint p) { return __uint_as_float(p << 16); }
__device__ __forceinline__ float bfhi(uint p) { return __uint_as_float(p & 0xffff0000u); }
__device__ __forceinline__ uint f2bf(float f) {
  uint u = __float_as_uint(f);
  return (u + 0x7fffu + ((u >> 16) & 1u)) >> 16;   // RTNE
}
__device__ __forceinline__ uint pack2(float lo, float hi) {
  return f2bf(lo) | (f2bf(hi) << 16);
}

// ---------------- threefry2x32 (JAX partitionable; verified) --------------
__device__ __forceinline__ void tf2x32(uint k0, uint k1, uint x0, uint x1,
                                       uint& o0, uint& o1) {
  uint ks2 = k0 ^ k1 ^ 0x1BD11BDAu;
  x0 += k0; x1 += k1;
#define TFR(r) { x0 += x1; x1 = (x1 << (r)) | (x1 >> (32 - (r))); x1 ^= x0; }
  TFR(13) TFR(15) TFR(26) TFR(6)
  x0 += k1;  x1 += ks2 + 1u;
  TFR(17) TFR(29) TFR(16) TFR(24)
  x0 += ks2; x1 += k0 + 2u;
  TFR(13) TFR(15) TFR(26) TFR(6)
  x0 += k0;  x1 += k1 + 3u;
  TFR(17) TFR(29) TFR(16) TFR(24)
  x0 += k1;  x1 += ks2 + 4u;
  TFR(13) TFR(15) TFR(26) TFR(6)
  x0 += ks2; x1 += k0 + 5u;
#undef TFR
  o0 = x0; o1 = x1;
}

// ---- fused prep: convx | masks | weight transpose | cursor init ----------
__global__ void prep_kernel(const float* __restrict__ x, uint* __restrict__ xb,
                            uint* __restrict__ m1, uint* __restrict__ m2,
                            const float* __restrict__ W0, const float* __restrict__ W1,
                            const float* __restrict__ Wss,
                            ushort* __restrict__ w0t, ushort* __restrict__ wcatT,
                            int* __restrict__ cursor) {
  int bid = blockIdx.x, tid = threadIdx.x;
  if (bid < CONVB) {
    if (bid == 0 && tid < NB) cursor[tid] = tid * CAP;
    int i = bid * 256 + tid;
    float2 v = ((const float2*)x)[i];
    xb[i] = pack2(v.x, v.y);
  } else if (bid < CONVB + MASKB) {
    int t = (bid - CONVB) * 256 + tid;
    uint a0, a1, b0, b1;
    tf2x32(0u, 42u, 0u, 0u, a0, a1);
    tf2x32(0u, 42u, 0u, 1u, b0, b1);
    bool second = (t >= NW);
    uint w  = second ? (uint)(t - NW) : (uint)t;
    uint k0 = second ? b0 : a0;
    uint k1 = second ? b1 : a1;
    uint base = w * 32u;
    uint word = 0u;
    for (int i = 0; i < 32; ++i) {
      uint o0, o1;
      tf2x32(k0, k1, 0u, base + (uint)i, o0, o1);
      word |= (uint)(((o0 ^ o1) >> 9) <= KEEP_THR) << i;
    }
    (second ? m2 : m1)[w] = word;
  } else {
    int idx = (bid - CONVB - MASKB) * 256 + tid;   // 0..30719
    if (idx < 16384) {
      int c = idx >> 7, k = idx & 127;
      w0t[idx] = (ushort)f2bf(W0[k * D + c]);
    } else {
      int j = idx - 16384;                         // 0..14335
      int c = j >> 7, k = j & 127;
      float v = (c < 40) ? W1[k * DO1 + c] : ((c < 48) ? 0.f : Wss[k * DO2 + (c - 48)]);
      wcatT[j] = (ushort)f2bf(v);
    }
  }
}

// ---- bin: edges -> buckets; entry = (row_local<<17 | col, val_bits) -------
__global__ void bin_kernel(const int* __restrict__ row, const int* __restrict__ col,
                           const float* __restrict__ val, int* __restrict__ cursor,
                           uint2* __restrict__ buck) {
  __shared__ int h[NB];
  __shared__ int base[NB];
  int tid = threadIdx.x;
  if (tid < NB) h[tid] = 0;
  __syncthreads();
  int e0 = blockIdx.x * 8192;
#pragma unroll 4
  for (int j = 0; j < 32; ++j) {
    int e = e0 + j * 256 + tid;
    if (e < NE) atomicAdd(&h[row[e] >> 11], 1);
  }
  __syncthreads();
  if (tid < NB) {
    int c = h[tid];
    base[tid] = c ? atomicAdd(&cursor[tid], c) : 0;
    h[tid] = 0;
  }
  __syncthreads();
#pragma unroll 4
  for (int j = 0; j < 32; ++j) {
    int e = e0 + j * 256 + tid;
    if (e < NE) {
      int r = row[e];
      int b = r >> 11;
      int k = atomicAdd(&h[b], 1);
      int idx = base[b] + k;
      int lim = (b + 1) * CAP;
      if (idx >= lim) idx = lim - 1;   // overflow guard (never at 18 sigma)
      buck[idx] = make_uint2(((uint)(r & 2047) << 17) | (uint)col[e],
                             __float_as_uint(val[e]));
    }
  }
}

// ---- csr: one block per bucket -> ptr + interleaved cv (localized writes) -
__global__ __launch_bounds__(1024) void csr_kernel(const uint2* __restrict__ buck,
                                                   const int* __restrict__ cursor,
                                                   int* __restrict__ ptr,
                                                   uint2* __restrict__ cv) {
  __shared__ int cnt[2048];
  __shared__ int sc[2048];
  __shared__ int cb[NB];
  int b = blockIdx.x, tid = threadIdx.x;
  if (tid < NB) cb[tid] = min(cursor[tid] - tid * CAP, CAP);
  int i0 = tid, i1 = tid + 1024;
  cnt[i0] = 0; cnt[i1] = 0;
  __syncthreads();
  int gbase = 0;
  for (int i = 0; i < b; ++i) gbase += cb[i];
  int n = cb[b];
  int src = b * CAP;
  for (int i = tid; i < n; i += 1024) atomicAdd(&cnt[buck[src + i].x >> 17], 1);
  __syncthreads();
  sc[i0] = cnt[i0]; sc[i1] = cnt[i1];
  __syncthreads();
  for (int off = 1; off < 2048; off <<= 1) {
    int v0 = (i0 >= off) ? sc[i0 - off] : 0;
    int v1 = (i1 >= off) ? sc[i1 - off] : 0;
    __syncthreads();
    sc[i0] += v0; sc[i1] += v1;
    __syncthreads();
  }
  int r0 = b * 2048;
  int s0 = sc[i0] - cnt[i0], s1 = sc[i1] - cnt[i1];
  if (r0 + i0 < NN) ptr[r0 + i0] = gbase + s0;
  if (r0 + i1 < NN) ptr[r0 + i1] = gbase + s1;
  if (b == 0 && tid == 0) ptr[NN] = NE;
  cnt[i0] = s0; cnt[i1] = s1;
  __syncthreads();
  for (int i = tid; i < n; i += 1024) {
    uint2 e = buck[src + i];
    int rl = e.x >> 17;
    int k = atomicAdd(&cnt[rl], 1);
    cv[gbase + k] = make_uint2(e.x & 0x1FFFFu, e.y);
  }
}

// ---- t = spmm(xb): 32 lanes/row, uint2/lane, 4x-unrolled edge loop (MLP) --
__global__ void spmm_x_kernel(const int* __restrict__ ptr, const uint2* __restrict__ cv,
                              const uint2* __restrict__ xb, uint2* __restrict__ t) {
  int r = blockIdx.x * 8 + (threadIdx.x >> 5);
  int k = threadIdx.x & 31;
  int s = ptr[r], e = ptr[r + 1];
  float a0 = 0.f, a1 = 0.f, a2 = 0.f, a3 = 0.f;
  int i = s;
  for (; i + 4 <= e; i += 4) {
    uint2 e0 = cv[i], e1 = cv[i + 1], e2 = cv[i + 2], e3 = cv[i + 3];
    uint2 p0 = xb[e0.x * 32 + k];
    uint2 p1 = xb[e1.x * 32 + k];
    uint2 p2 = xb[e2.x * 32 + k];
    uint2 p3 = xb[e3.x * 32 + k];
    float v0 = __uint_as_float(e0.y), v1 = __uint_as_float(e1.y);
    float v2 = __uint_as_float(e2.y), v3 = __uint_as_float(e3.y);
    a0 += v0 * bflo(p0.x); a1 += v0 * bfhi(p0.x);
    a2 += v0 * bflo(p0.y); a3 += v0 * bfhi(p0.y);
    a0 += v1 * bflo(p1.x); a1 += v1 * bfhi(p1.x);
    a2 += v1 * bflo(p1.y); a3 += v1 * bfhi(p1.y);
    a0 += v2 * bflo(p2.x); a1 += v2 * bfhi(p2.x);
    a2 += v2 * bflo(p2.y); a3 += v2 * bfhi(p2.y);
    a0 += v3 * bflo(p3.x); a1 += v3 * bfhi(p3.x);
    a2 += v3 * bflo(p3.y); a3 += v3 * bfhi(p3.y);
  }
  for (; i < e; ++i) {
    uint2 ev = cv[i];
    float v = __uint_as_float(ev.y);
    uint2 p = xb[ev.x * 32 + k];
    a0 += v * bflo(p.x); a1 += v * bfhi(p.x);
    a2 += v * bflo(p.y); a3 += v * bfhi(p.y);
  }
  t[r * 32 + k] = make_uint2(pack2(a0, a1), pack2(a2, a3));
}

// ---- pass A (MFMA): U = relu(T@W0); Z^T = Wcat^T @ U^T (dropout-masked) ----
#define SWZ(row, byte) ((row) * 256 + ((byte) ^ ((((row) >> 1) & 7) << 4)))
__global__ __launch_bounds__(512, 4) void pass_a_kernel(
    const uint* __restrict__ tb, const ushort* __restrict__ w0t,
    const ushort* __restrict__ wcatT,
    const uint* __restrict__ m1, const uint* __restrict__ m2,
    ushort* __restrict__ zz) {
  __shared__ __align__(16) char ldsb[69632];
  uint* mlds = (uint*)(ldsb + 65536);          // [2][128][4]

  int t = threadIdx.x;
  int r0 = blockIdx.x * 128;
  int wid = t >> 6, l = t & 63, lc = l & 15, lk = l >> 4;

#pragma unroll
  for (int i = 0; i < 4; ++i) {
    int lin = i * 512 + t;            // 0..2047
    int row = lin >> 4, seg = lin & 15;
    int gr = r0 + row;
    uint4 v = make_uint4(0, 0, 0, 0);
    if (gr < NN) v = ((const uint4*)(tb + (size_t)gr * 64))[seg];
    *(uint4*)&ldsb[SWZ(row, seg * 16)] = v;
    uint4 w = ((const uint4*)w0t)[lin];
    *(uint4*)&ldsb[32768 + SWZ(row, seg * 16)] = w;
  }
#pragma unroll
  for (int i = 0; i < 2; ++i) {
    int idx = t;
    int row = idx >> 2, word = idx & 3;
    int gr = r0 + row;
    uint v = 0;
    if (gr < NN) v = (i == 0 ? m1 : m2)[gr * 4 + word];
    mlds[i * 512 + idx] = v;
  }
  __syncthreads();

  short8 af[4];
#pragma unroll
  for (int s = 0; s < 4; ++s) {
    U4S8 tmp; tmp.u = *(uint4*)&ldsb[SWZ(16 * wid + lc, 64 * s + 16 * lk)];
    af[s] = tmp.s;
  }
  f32x4 acc[8];
#pragma unroll
  for (int n = 0; n < 8; ++n) acc[n] = (f32x4)(0.f);
#pragma unroll
  for (int n = 0; n < 8; ++n) {
#pragma unroll
    for (int s = 0; s < 4; ++s) {
      U4S8 tmp; tmp.u = *(uint4*)&ldsb[32768 + SWZ(16 * n + lc, 64 * s + 16 * lk)];
      acc[n] = __builtin_amdgcn_mfma_f32_16x16x32_bf16(af[s], tmp.s, acc[n], 0, 0, 0);
    }
  }
  __syncthreads();

#pragma unroll
  for (int reg = 0; reg < 4; ++reg) {
    int row = 16 * wid + 4 * lk + reg;
    uint4 w1q = *(uint4*)&mlds[row * 4];
    uint4 w2q = *(uint4*)&mlds[512 + row * 4];
    uint w1a[4] = {w1q.x, w1q.y, w1q.z, w1q.w};
    uint w2a[4] = {w2q.x, w2q.y, w2q.z, w2q.w};
#pragma unroll
    for (int n = 0; n < 8; ++n) {
      float v = fmaxf(acc[n][reg], 0.f) * 1.25f;
      ushort ub = (ushort)f2bf(v);
      int bit = (n & 1) * 16 + lc;
      ushort u1 = ((w1a[n >> 1] >> bit) & 1u) ? ub : (ushort)0;
      ushort u2 = ((w2a[n >> 1] >> bit) & 1u) ? ub : (ushort)0;
      int ad = SWZ(row, 32 * n + 2 * lc);
      *(ushort*)&ldsb[ad] = u1;
      *(ushort*)&ldsb[32768 + ad] = u2;
    }
  }
  __syncthreads();

  f32x4 acc2[7];
#pragma unroll
  for (int n = 0; n < 7; ++n) acc2[n] = (f32x4)(0.f);
#pragma unroll
  for (int n2 = 0; n2 < 7; ++n2) {
    int ubase = (n2 < 3) ? 0 : 32768;
#pragma unroll
    for (int s = 0; s < 4; ++s) {
      U4S8 a2; a2.u = ((const uint4*)wcatT)[(16 * n2 + lc) * 16 + 4 * s + lk];
      U4S8 b2; b2.u = *(uint4*)&ldsb[ubase + SWZ(16 * wid + lc, 64 * s + 16 * lk)];
      acc2[n2] = __builtin_amdgcn_mfma_f32_16x16x32_bf16(a2.s, b2.s, acc2[n2], 0, 0, 0);
    }
  }

  int r = r0 + 16 * wid + lc;
  if (r < NN) {
#pragma unroll
    for (int n2 = 0; n2 < 7; ++n2) {
      if (n2 == 2 && lk >= 2) continue;          // W1 pad cols 40..47
      int cb = 16 * n2 + 4 * lk;
      if (n2 >= 3) cb -= 8;
      uint2 v = make_uint2(pack2(acc2[n2][0], acc2[n2][1]),
                           pack2(acc2[n2][2], acc2[n2][3]));
      *(uint2*)(zz + (size_t)r * ZC + cb) = v;
    }
  }
}

// ---- out = spmm(z): 32 lanes/row (26 active), 4x-unrolled edge loop -------
__global__ void gather_out_kernel(const int* __restrict__ ptr, const uint2* __restrict__ cv,
                                  const uint2* __restrict__ zp, float* __restrict__ out) {
  int r = blockIdx.x * 8 + (threadIdx.x >> 5);
  int k = threadIdx.x & 31;
  if (k >= 26) return;
  int s = ptr[r], e = ptr[r + 1];
  float a0 = 0.f, a1 = 0.f, a2 = 0.f, a3 = 0.f;
  int i = s;
  for (; i + 4 <= e; i += 4) {
    uint2 e0 = cv[i], e1 = cv[i + 1], e2 = cv[i + 2], e3 = cv[i + 3];
    uint2 p0 = zp[e0.x * 26 + k];
    uint2 p1 = zp[e1.x * 26 + k];
    uint2 p2 = zp[e2.x * 26 + k];
    uint2 p3 = zp[e3.x * 26 + k];
    float v0 = __uint_as_float(e0.y), v1 = __uint_as_float(e1.y);
    float v2 = __uint_as_float(e2.y), v3 = __uint_as_float(e3.y);
    a0 += v0 * bflo(p0.x); a1 += v0 * bfhi(p0.x);
    a2 += v0 * bflo(p0.y); a3 += v0 * bfhi(p0.y);
    a0 += v1 * bflo(p1.x); a1 += v1 * bfhi(p1.x);
    a2 += v1 * bflo(p1.y); a3 += v1 * bfhi(p1.y);
    a0 += v2 * bflo(p2.x); a1 += v2 * bfhi(p2.x);
    a2 += v2 * bflo(p2.y); a3 += v2 * bfhi(p2.y);
    a0 += v3 * bflo(p3.x); a1 += v3 * bfhi(p3.x);
    a2 += v3 * bflo(p3.y); a3 += v3 * bfhi(p3.y);
  }
  for (; i < e; ++i) {
    uint2 ev = cv[i];
    float v = __uint_as_float(ev.y);
    uint2 p = zp[ev.x * 26 + k];
    a0 += v * bflo(p.x); a1 += v * bfhi(p.x);
    a2 += v * bflo(p.y); a3 += v * bfhi(p.y);
  }
  if (k < 10) {
    *(float4*)(out + (size_t)r * DO1 + 4 * k) = make_float4(a0, a1, a2, a3);
  } else {
    *(float4*)(out + OUT_S_OFF + (size_t)r * DO2 + 4 * (k - 10)) = make_float4(a0, a1, a2, a3);
  }
}

// ---------------- launch ----------------
extern "C" void kernel_launch(void* const* d_in, const int* in_sizes, int n_in,
                              void* d_out, int out_size, void* d_ws, size_t ws_size,
                              hipStream_t stream) {
  const float* x       = (const float*)d_in[0];
  const int*   adj_row = (const int*)d_in[1];
  const int*   adj_col = (const int*)d_in[2];
  const float* adj_val = (const float*)d_in[3];
  const float* W0      = (const float*)d_in[4];
  const float* W1      = (const float*)d_in[5];
  const float* Wss     = (const float*)d_in[6];
  float* out = (float*)d_out;

  char* ws = (char*)d_ws;
  uint*   t_bf  = (uint*)(ws + 0);           // 25,600,000 B bf16 t
  uint2*  buck  = (uint2*)(ws + 0);          // 14,112,000 B (aliases t_bf; dead before spmm_x)
  uint*   xb    = (uint*)(ws + 25600000);    // 25,600,000 B bf16 x
  ushort* zz    = (ushort*)(ws + 25600000);  // 20,800,000 B bf16 z (aliases xb; xb dead)
  uint*   m1    = (uint*)(ws + 51200000);    //  1,600,000 B
  uint*   m2    = (uint*)(ws + 52800000);    //  1,600,000 B
  int*    ptr   = (int*)(ws + 54400000);     //    400,004 B
  ushort* w0t   = (ushort*)(ws + 54800016);  //     32,768 B
  ushort* wcatT = (ushort*)(ws + 54832784);  //     28,672 B
  int*    curs  = (int*)(ws + 54861456);     //        196 B
  uint2*  cv    = (uint2*)(ws + 55600016);   // 12,800,000 B (end 68,400,016)

  prep_kernel<<<CONVB + MASKB + 120, 256, 0, stream>>>(x, xb, m1, m2, W0, W1, Wss,
                                                       w0t, wcatT, curs);
  bin_kernel<<<196, 256, 0, stream>>>(adj_row, adj_col, adj_val, curs, buck);
  csr_kernel<<<NB, 1024, 0, stream>>>(buck, curs, ptr, cv);
  spmm_x_kernel<<<12500, 256, 0, stream>>>(ptr, cv, (const uint2*)xb, (uint2*)t_bf);
  pass_a_kernel<<<782, 512, 0, stream>>>(t_bf, w0t, wcatT, m1, m2, zz);
  gather_out_kernel<<<12500, 256, 0, stream>>>(ptr, cv, (const uint2*)zz, out);
}

// Round 9
// 282.750 us; speedup vs baseline: 4.7305x; 1.0926x over previous
//
#include <hip/hip_runtime.h>
#include <stdint.h>

// net_gcn_multitask — MI355X.
//   memset: bucket cursors = 0
//   bin_conv: [bin edges->buckets | xb=bf16(x) | w0t/wcatT]   (regime-packed)
//   csr_mask: [per-bucket CSR build | threefry masks]          (regime-packed)
//   spmm_x: t = spmm(xb)              [32-lane/row gather, 4x unrolled]
//   pass_a: U=relu(t@W0) [MFMA]; z=[drop1(U)@W1 | drop2(U)@Wss] [MFMA]
//   gather_out: h|s = spmm(z)         [32-lane/row gather, 4x unrolled]

#define NN 100000
#define NE 1600000
#define D 128
#define NW 400000
#define ZC 104
#define DO1 40
#define DO2 64
#define OUT_S_OFF 4000000
#define KEEP_THR 6710886u
#define NB 49          // buckets of 2048 rows
#define CAP 36000      // entries per bucket region (mean 32653, ~18 sigma)
#define BINB 196
#define CONVB 12500    // 12500*256 float4 = 12.8M floats
#define CSRB 49
#define MASKB1K 782    // ceil(800000/1024)

typedef unsigned int uint;
typedef __attribute__((ext_vector_type(4))) float f32x4;
typedef __attribute__((ext_vector_type(8))) short short8;
union U4S8 { uint4 u; short8 s; };

// ---------------- bf16 helpers ----------------
__device__ __forceinline__ float bflo(uint p) { return __uint_as_float(p << 16); }
__device__ __forceinline__ float bfhi(uint p) { return __uint_as_float(p & 0xffff0000u); }
__device__ __forceinline__ uint f2bf(float f) {
  uint u = __float_as_uint(f);
  return (u + 0x7fffu + ((u >> 16) & 1u)) >> 16;   // RTNE
}
__device__ __forceinline__ uint pack2(float lo, float hi) {
  return f2bf(lo) | (f2bf(hi) << 16);
}

// ---------------- threefry2x32 (JAX partitionable; verified) --------------
__device__ __forceinline__ void tf2x32(uint k0, uint k1, uint x0, uint x1,
                                       uint& o0, uint& o1) {
  uint ks2 = k0 ^ k1 ^ 0x1BD11BDAu;
  x0 += k0; x1 += k1;
#define TFR(r) { x0 += x1; x1 = (x1 << (r)) | (x1 >> (32 - (r))); x1 ^= x0; }
  TFR(13) TFR(15) TFR(26) TFR(6)
  x0 += k1;  x1 += ks2 + 1u;
  TFR(17) TFR(29) TFR(16) TFR(24)
  x0 += ks2; x1 += k0 + 2u;
  TFR(13) TFR(15) TFR(26) TFR(6)
  x0 += k0;  x1 += k1 + 3u;
  TFR(17) TFR(29) TFR(16) TFR(24)
  x0 += k1;  x1 += ks2 + 4u;
  TFR(13) TFR(15) TFR(26) TFR(6)
  x0 += ks2; x1 += k0 + 5u;
#undef TFR
  o0 = x0; o1 = x1;
}

// ---- bin_conv: [bin | convx float4 | weight transpose], 256 thr ----------
__global__ void bin_conv_kernel(const int* __restrict__ row, const int* __restrict__ col,
                                const float* __restrict__ val, int* __restrict__ cursor,
                                uint2* __restrict__ buck,
                                const float* __restrict__ x, uint* __restrict__ xb,
                                const float* __restrict__ W0, const float* __restrict__ W1,
                                const float* __restrict__ Wss,
                                ushort* __restrict__ w0t, ushort* __restrict__ wcatT) {
  int bid = blockIdx.x, tid = threadIdx.x;
  if (bid < BINB) {
    __shared__ int h[NB];
    __shared__ int base[NB];
    if (tid < NB) h[tid] = 0;
    __syncthreads();
    int e0 = bid * 8192;
#pragma unroll 4
    for (int j = 0; j < 32; ++j) {
      int e = e0 + j * 256 + tid;
      if (e < NE) atomicAdd(&h[row[e] >> 11], 1);
    }
    __syncthreads();
    if (tid < NB) {
      int c = h[tid];
      base[tid] = c ? (tid * CAP + atomicAdd(&cursor[tid], c)) : 0;
      h[tid] = 0;
    }
    __syncthreads();
#pragma unroll 4
    for (int j = 0; j < 32; ++j) {
      int e = e0 + j * 256 + tid;
      if (e < NE) {
        int r = row[e];
        int b = r >> 11;
        int k = atomicAdd(&h[b], 1);
        int idx = base[b] + k;
        int lim = (b + 1) * CAP;
        if (idx >= lim) idx = lim - 1;   // overflow guard (never at 18 sigma)
        buck[idx] = make_uint2(((uint)(r & 2047) << 17) | (uint)col[e],
                               __float_as_uint(val[e]));
      }
    }
  } else if (bid < BINB + CONVB) {
    int i = (bid - BINB) * 256 + tid;   // float4 index, 3.2M
    float4 v = ((const float4*)x)[i];
    ((uint2*)xb)[i] = make_uint2(pack2(v.x, v.y), pack2(v.z, v.w));
  } else {
    int idx = (bid - BINB - CONVB) * 256 + tid;   // 0..30719
    if (idx < 16384) {
      int c = idx >> 7, k = idx & 127;
      w0t[idx] = (ushort)f2bf(W0[k * D + c]);
    } else {
      int j = idx - 16384;                         // 0..14335
      int c = j >> 7, k = j & 127;
      float v = (c < 40) ? W1[k * DO1 + c] : ((c < 48) ? 0.f : Wss[k * DO2 + (c - 48)]);
      wcatT[j] = (ushort)f2bf(v);
    }
  }
}

// ---- csr_mask: [per-bucket CSR | threefry masks], 1024 thr ---------------
__global__ __launch_bounds__(1024) void csr_mask_kernel(
    const uint2* __restrict__ buck, const int* __restrict__ cursor,
    int* __restrict__ ptr, uint2* __restrict__ cv,
    uint* __restrict__ m1, uint* __restrict__ m2) {
  int bid = blockIdx.x, tid = threadIdx.x;
  if (bid >= CSRB) {
    int t = (bid - CSRB) * 1024 + tid;
    if (t >= 2 * NW) return;
    uint a0, a1, b0, b1;
    tf2x32(0u, 42u, 0u, 0u, a0, a1);
    tf2x32(0u, 42u, 0u, 1u, b0, b1);
    bool second = (t >= NW);
    uint w  = second ? (uint)(t - NW) : (uint)t;
    uint k0 = second ? b0 : a0;
    uint k1 = second ? b1 : a1;
    uint base = w * 32u;
    uint word = 0u;
    for (int i = 0; i < 32; ++i) {
      uint o0, o1;
      tf2x32(k0, k1, 0u, base + (uint)i, o0, o1);
      word |= (uint)(((o0 ^ o1) >> 9) <= KEEP_THR) << i;
    }
    (second ? m2 : m1)[w] = word;
    return;
  }
  __shared__ int cnt[2048];
  __shared__ int sc[2048];
  __shared__ int cb[NB];
  int b = bid;
  if (tid < NB) cb[tid] = min(cursor[tid], CAP);
  int i0 = tid, i1 = tid + 1024;
  cnt[i0] = 0; cnt[i1] = 0;
  __syncthreads();
  int gbase = 0;
  for (int i = 0; i < b; ++i) gbase += cb[i];
  int n = cb[b];
  int src = b * CAP;
  for (int i = tid; i < n; i += 1024) atomicAdd(&cnt[buck[src + i].x >> 17], 1);
  __syncthreads();
  sc[i0] = cnt[i0]; sc[i1] = cnt[i1];
  __syncthreads();
  for (int off = 1; off < 2048; off <<= 1) {
    int v0 = (i0 >= off) ? sc[i0 - off] : 0;
    int v1 = (i1 >= off) ? sc[i1 - off] : 0;
    __syncthreads();
    sc[i0] += v0; sc[i1] += v1;
    __syncthreads();
  }
  int r0 = b * 2048;
  int s0 = sc[i0] - cnt[i0], s1 = sc[i1] - cnt[i1];
  if (r0 + i0 < NN) ptr[r0 + i0] = gbase + s0;
  if (r0 + i1 < NN) ptr[r0 + i1] = gbase + s1;
  if (b == 0 && tid == 0) ptr[NN] = NE;
  cnt[i0] = s0; cnt[i1] = s1;
  __syncthreads();
  for (int i = tid; i < n; i += 1024) {
    uint2 e = buck[src + i];
    int rl = e.x >> 17;
    int k = atomicAdd(&cnt[rl], 1);
    cv[gbase + k] = make_uint2(e.x & 0x1FFFFu, e.y);
  }
}

// ---- t = spmm(xb): 32 lanes/row, uint2/lane, 4x-unrolled edge loop (MLP) --
__global__ void spmm_x_kernel(const int* __restrict__ ptr, const uint2* __restrict__ cv,
                              const uint2* __restrict__ xb, uint2* __restrict__ t) {
  int r = blockIdx.x * 8 + (threadIdx.x >> 5);
  int k = threadIdx.x & 31;
  int s = ptr[r], e = ptr[r + 1];
  float a0 = 0.f, a1 = 0.f, a2 = 0.f, a3 = 0.f;
  int i = s;
  for (; i + 4 <= e; i += 4) {
    uint2 e0 = cv[i], e1 = cv[i + 1], e2 = cv[i + 2], e3 = cv[i + 3];
    uint2 p0 = xb[e0.x * 32 + k];
    uint2 p1 = xb[e1.x * 32 + k];
    uint2 p2 = xb[e2.x * 32 + k];
    uint2 p3 = xb[e3.x * 32 + k];
    float v0 = __uint_as_float(e0.y), v1 = __uint_as_float(e1.y);
    float v2 = __uint_as_float(e2.y), v3 = __uint_as_float(e3.y);
    a0 += v0 * bflo(p0.x); a1 += v0 * bfhi(p0.x);
    a2 += v0 * bflo(p0.y); a3 += v0 * bfhi(p0.y);
    a0 += v1 * bflo(p1.x); a1 += v1 * bfhi(p1.x);
    a2 += v1 * bflo(p1.y); a3 += v1 * bfhi(p1.y);
    a0 += v2 * bflo(p2.x); a1 += v2 * bfhi(p2.x);
    a2 += v2 * bflo(p2.y); a3 += v2 * bfhi(p2.y);
    a0 += v3 * bflo(p3.x); a1 += v3 * bfhi(p3.x);
    a2 += v3 * bflo(p3.y); a3 += v3 * bfhi(p3.y);
  }
  for (; i < e; ++i) {
    uint2 ev = cv[i];
    float v = __uint_as_float(ev.y);
    uint2 p = xb[ev.x * 32 + k];
    a0 += v * bflo(p.x); a1 += v * bfhi(p.x);
    a2 += v * bflo(p.y); a3 += v * bfhi(p.y);
  }
  t[r * 32 + k] = make_uint2(pack2(a0, a1), pack2(a2, a3));
}

// ---- pass A (MFMA): U = relu(T@W0); Z^T = Wcat^T @ U^T (dropout-masked) ----
#define SWZ(row, byte) ((row) * 256 + ((byte) ^ ((((row) >> 1) & 7) << 4)))
__global__ __launch_bounds__(512, 4) void pass_a_kernel(
    const uint* __restrict__ tb, const ushort* __restrict__ w0t,
    const ushort* __restrict__ wcatT,
    const uint* __restrict__ m1, const uint* __restrict__ m2,
    ushort* __restrict__ zz) {
  __shared__ __align__(16) char ldsb[69632];
  uint* mlds = (uint*)(ldsb + 65536);          // [2][128][4]

  int t = threadIdx.x;
  int r0 = blockIdx.x * 128;
  int wid = t >> 6, l = t & 63, lc = l & 15, lk = l >> 4;

#pragma unroll
  for (int i = 0; i < 4; ++i) {
    int lin = i * 512 + t;            // 0..2047
    int row = lin >> 4, seg = lin & 15;
    int gr = r0 + row;
    uint4 v = make_uint4(0, 0, 0, 0);
    if (gr < NN) v = ((const uint4*)(tb + (size_t)gr * 64))[seg];
    *(uint4*)&ldsb[SWZ(row, seg * 16)] = v;
    uint4 w = ((const uint4*)w0t)[lin];
    *(uint4*)&ldsb[32768 + SWZ(row, seg * 16)] = w;
  }
#pragma unroll
  for (int i = 0; i < 2; ++i) {
    int idx = t;
    int row = idx >> 2, word = idx & 3;
    int gr = r0 + row;
    uint v = 0;
    if (gr < NN) v = (i == 0 ? m1 : m2)[gr * 4 + word];
    mlds[i * 512 + idx] = v;
  }
  __syncthreads();

  short8 af[4];
#pragma unroll
  for (int s = 0; s < 4; ++s) {
    U4S8 tmp; tmp.u = *(uint4*)&ldsb[SWZ(16 * wid + lc, 64 * s + 16 * lk)];
    af[s] = tmp.s;
  }
  f32x4 acc[8];
#pragma unroll
  for (int n = 0; n < 8; ++n) acc[n] = (f32x4)(0.f);
#pragma unroll
  for (int n = 0; n < 8; ++n) {
#pragma unroll
    for (int s = 0; s < 4; ++s) {
      U4S8 tmp; tmp.u = *(uint4*)&ldsb[32768 + SWZ(16 * n + lc, 64 * s + 16 * lk)];
      acc[n] = __builtin_amdgcn_mfma_f32_16x16x32_bf16(af[s], tmp.s, acc[n], 0, 0, 0);
    }
  }
  __syncthreads();

#pragma unroll
  for (int reg = 0; reg < 4; ++reg) {
    int row = 16 * wid + 4 * lk + reg;
    uint4 w1q = *(uint4*)&mlds[row * 4];
    uint4 w2q = *(uint4*)&mlds[512 + row * 4];
    uint w1a[4] = {w1q.x, w1q.y, w1q.z, w1q.w};
    uint w2a[4] = {w2q.x, w2q.y, w2q.z, w2q.w};
#pragma unroll
    for (int n = 0; n < 8; ++n) {
      float v = fmaxf(acc[n][reg], 0.f) * 1.25f;
      ushort ub = (ushort)f2bf(v);
      int bit = (n & 1) * 16 + lc;
      ushort u1 = ((w1a[n >> 1] >> bit) & 1u) ? ub : (ushort)0;
      ushort u2 = ((w2a[n >> 1] >> bit) & 1u) ? ub : (ushort)0;
      int ad = SWZ(row, 32 * n + 2 * lc);
      *(ushort*)&ldsb[ad] = u1;
      *(ushort*)&ldsb[32768 + ad] = u2;
    }
  }
  __syncthreads();

  f32x4 acc2[7];
#pragma unroll
  for (int n = 0; n < 7; ++n) acc2[n] = (f32x4)(0.f);
#pragma unroll
  for (int n2 = 0; n2 < 7; ++n2) {
    int ubase = (n2 < 3) ? 0 : 32768;
#pragma unroll
    for (int s = 0; s < 4; ++s) {
      U4S8 a2; a2.u = ((const uint4*)wcatT)[(16 * n2 + lc) * 16 + 4 * s + lk];
      U4S8 b2; b2.u = *(uint4*)&ldsb[ubase + SWZ(16 * wid + lc, 64 * s + 16 * lk)];
      acc2[n2] = __builtin_amdgcn_mfma_f32_16x16x32_bf16(a2.s, b2.s, acc2[n2], 0, 0, 0);
    }
  }

  int r = r0 + 16 * wid + lc;
  if (r < NN) {
#pragma unroll
    for (int n2 = 0; n2 < 7; ++n2) {
      if (n2 == 2 && lk >= 2) continue;          // W1 pad cols 40..47
      int cb = 16 * n2 + 4 * lk;
      if (n2 >= 3) cb -= 8;
      uint2 v = make_uint2(pack2(acc2[n2][0], acc2[n2][1]),
                           pack2(acc2[n2][2], acc2[n2][3]));
      *(uint2*)(zz + (size_t)r * ZC + cb) = v;
    }
  }
}

// ---- out = spmm(z): 32 lanes/row (26 active), 4x-unrolled edge loop -------
__global__ void gather_out_kernel(const int* __restrict__ ptr, const uint2* __restrict__ cv,
                                  const uint2* __restrict__ zp, float* __restrict__ out) {
  int r = blockIdx.x * 8 + (threadIdx.x >> 5);
  int k = threadIdx.x & 31;
  if (k >= 26) return;
  int s = ptr[r], e = ptr[r + 1];
  float a0 = 0.f, a1 = 0.f, a2 = 0.f, a3 = 0.f;
  int i = s;
  for (; i + 4 <= e; i += 4) {
    uint2 e0 = cv[i], e1 = cv[i + 1], e2 = cv[i + 2], e3 = cv[i + 3];
    uint2 p0 = zp[e0.x * 26 + k];
    uint2 p1 = zp[e1.x * 26 + k];
    uint2 p2 = zp[e2.x * 26 + k];
    uint2 p3 = zp[e3.x * 26 + k];
    float v0 = __uint_as_float(e0.y), v1 = __uint_as_float(e1.y);
    float v2 = __uint_as_float(e2.y), v3 = __uint_as_float(e3.y);
    a0 += v0 * bflo(p0.x); a1 += v0 * bfhi(p0.x);
    a2 += v0 * bflo(p0.y); a3 += v0 * bfhi(p0.y);
    a0 += v1 * bflo(p1.x); a1 += v1 * bfhi(p1.x);
    a2 += v1 * bflo(p1.y); a3 += v1 * bfhi(p1.y);
    a0 += v2 * bflo(p2.x); a1 += v2 * bfhi(p2.x);
    a2 += v2 * bflo(p2.y); a3 += v2 * bfhi(p2.y);
    a0 += v3 * bflo(p3.x); a1 += v3 * bfhi(p3.x);
    a2 += v3 * bflo(p3.y); a3 += v3 * bfhi(p3.y);
  }
  for (; i < e; ++i) {
    uint2 ev = cv[i];
    float v = __uint_as_float(ev.y);
    uint2 p = zp[ev.x * 26 + k];
    a0 += v * bflo(p.x); a1 += v * bfhi(p.x);
    a2 += v * bflo(p.y); a3 += v * bfhi(p.y);
  }
  if (k < 10) {
    *(float4*)(out + (size_t)r * DO1 + 4 * k) = make_float4(a0, a1, a2, a3);
  } else {
    *(float4*)(out + OUT_S_OFF + (size_t)r * DO2 + 4 * (k - 10)) = make_float4(a0, a1, a2, a3);
  }
}

// ---------------- launch ----------------
extern "C" void kernel_launch(void* const* d_in, const int* in_sizes, int n_in,
                              void* d_out, int out_size, void* d_ws, size_t ws_size,
                              hipStream_t stream) {
  const float* x       = (const float*)d_in[0];
  const int*   adj_row = (const int*)d_in[1];
  const int*   adj_col = (const int*)d_in[2];
  const float* adj_val = (const float*)d_in[3];
  const float* W0      = (const float*)d_in[4];
  const float* W1      = (const float*)d_in[5];
  const float* Wss     = (const float*)d_in[6];
  float* out = (float*)d_out;

  char* ws = (char*)d_ws;
  uint*   t_bf  = (uint*)(ws + 0);           // 25,600,000 B bf16 t
  uint2*  buck  = (uint2*)(ws + 0);          // 14,112,000 B (aliases t_bf; dead before spmm_x)
  uint*   xb    = (uint*)(ws + 25600000);    // 25,600,000 B bf16 x
  ushort* zz    = (ushort*)(ws + 25600000);  // 20,800,000 B bf16 z (aliases xb; xb dead)
  uint*   m1    = (uint*)(ws + 51200000);    //  1,600,000 B
  uint*   m2    = (uint*)(ws + 52800000);    //  1,600,000 B
  int*    ptr   = (int*)(ws + 54400000);     //    400,004 B
  ushort* w0t   = (ushort*)(ws + 54800016);  //     32,768 B
  ushort* wcatT = (ushort*)(ws + 54832784);  //     28,672 B
  int*    curs  = (int*)(ws + 54861456);     //        196 B
  uint2*  cv    = (uint2*)(ws + 55600016);   // 12,800,000 B (end 68,400,016)

  hipMemsetAsync(curs, 0, NB * sizeof(int), stream);
  bin_conv_kernel<<<BINB + CONVB + 120, 256, 0, stream>>>(
      adj_row, adj_col, adj_val, curs, buck, x, xb, W0, W1, Wss, w0t, wcatT);
  csr_mask_kernel<<<CSRB + MASKB1K, 1024, 0, stream>>>(buck, curs, ptr, cv, m1, m2);
  spmm_x_kernel<<<12500, 256, 0, stream>>>(ptr, cv, (const uint2*)xb, (uint2*)t_bf);
  pass_a_kernel<<<782, 512, 0, stream>>>(t_bf, w0t, wcatT, m1, m2, zz);
  gather_out_kernel<<<12500, 256, 0, stream>>>(ptr, cv, (const uint2*)zz, out);
}